// Round 12
// baseline (204.005 us; speedup 1.0000x reference)
//
#include <hip/hip_runtime.h>

#define DEV __device__ __forceinline__

typedef __bf16 bf16;
typedef bf16 bf16x4 __attribute__((ext_vector_type(4)));
typedef bf16 bf16x8 __attribute__((ext_vector_type(8)));
typedef float f32x4 __attribute__((ext_vector_type(4)));

DEV f32x4 mfma16(bf16x8 a, bf16x8 b, f32x4 c) {
  return __builtin_amdgcn_mfma_f32_16x16x32_bf16(a, b, c, 0, 0, 0);
}

DEV void gload_lds16(const bf16* g, bf16* l) {
  __builtin_amdgcn_global_load_lds((const __attribute__((address_space(1))) void*)g,
                                   (__attribute__((address_space(3))) void*)l, 16, 0, 0);
}

#define PH_BAR __builtin_amdgcn_s_barrier()
#define VM(NSTR) asm volatile("s_waitcnt vmcnt(" NSTR ")" ::: "memory")
#define WAITBAR(NSTR) asm volatile("s_waitcnt vmcnt(" NSTR ")\n\ts_barrier" ::: "memory")

// tanh-form GELU, exp2+rcp based (~8 VALU ops, overflow-safe both tails).
DEV float fast_gelu(float x) {
  const float z = x * x;
  const float w = __builtin_fmaf(z, 0.1029353f, 2.3019853f);
  const float e = __builtin_amdgcn_exp2f(x * w);
  const float r = __builtin_amdgcn_rcpf(1.0f + e);
  return x - x * r;
}

// ---------------- fused LayerNorm (rows) + all weight casts ----------------
__global__ __launch_bounds__(256) void ln_cast_all(
    const float* __restrict__ x,
    const float* __restrict__ ln1w, const float* __restrict__ ln1b,
    const float* __restrict__ ln2w, const float* __restrict__ ln2b,
    bf16* __restrict__ h1, bf16* __restrict__ h2,
    const float* __restrict__ Wqkv_f, const float* __restrict__ W1_f,
    const float* __restrict__ Wo_f, const float* __restrict__ W2_f,
    bf16* __restrict__ wQKV, bf16* __restrict__ w1, bf16* __restrict__ wCat)
{
  const int b = blockIdx.x, t = threadIdx.x;
  if (b < 4096) {
    __shared__ float red[2][4];
    const int lane = t & 63, wave = t >> 6;
    const float4 v = ((const float4*)(x + (size_t)b * 1024))[t];
    float vv[4] = {v.x, v.y, v.z, v.w};
    float s = vv[0] + vv[1] + vv[2] + vv[3];
    float q = vv[0]*vv[0] + vv[1]*vv[1] + vv[2]*vv[2] + vv[3]*vv[3];
    #pragma unroll
    for (int o = 32; o; o >>= 1) { s += __shfl_xor(s, o); q += __shfl_xor(q, o); }
    if (lane == 0) { red[0][wave] = s; red[1][wave] = q; }
    __syncthreads();
    s = red[0][0] + red[0][1] + red[0][2] + red[0][3];
    q = red[1][0] + red[1][1] + red[1][2] + red[1][3];
    const float mu = s * (1.0f / 1024.0f);
    const float var = q * (1.0f / 1024.0f) - mu * mu;
    const float rs = rsqrtf(var + 1e-5f);
    bf16x4 o1, o2;
    #pragma unroll
    for (int j = 0; j < 4; ++j) {
      const int i = t * 4 + j;
      const float xh = (vv[j] - mu) * rs;
      o1[j] = (bf16)(xh * ln1w[i] + ln1b[i]);
      o2[j] = (bf16)(xh * ln2w[i] + ln2b[i]);
    }
    *(bf16x4*)&h1[(size_t)b * 1024 + t * 4] = o1;
    *(bf16x4*)&h2[(size_t)b * 1024 + t * 4] = o2;
    return;
  }
  const int cb = b - 4096;
  if (cb < 3072) {
    const int i = cb * 256 + t;
    const float4 v = ((const float4*)Wqkv_f)[i];
    bf16x4 o = {(bf16)v.x, (bf16)v.y, (bf16)v.z, (bf16)v.w};
    ((bf16x4*)wQKV)[i] = o;
  } else if (cb < 7168) {
    const int i = (cb - 3072) * 256 + t;
    const float4 v = ((const float4*)W1_f)[i];
    bf16x4 o = {(bf16)v.x, (bf16)v.y, (bf16)v.z, (bf16)v.w};
    ((bf16x4*)w1)[i] = o;
  } else if (cb < 8192) {
    const int row = cb - 7168;
    const float4 v = *(const float4*)&Wo_f[(size_t)row * 1024 + t * 4];
    bf16x4 o = {(bf16)v.x, (bf16)v.y, (bf16)v.z, (bf16)v.w};
    *(bf16x4*)&wCat[(size_t)row * 5120 + t * 4] = o;
  } else {
    const int row = cb - 8192;
    #pragma unroll
    for (int k = 0; k < 4; ++k) {
      const int col = t * 4 + k * 1024;
      const float4 v = *(const float4*)&W2_f[(size_t)row * 4096 + col];
      bf16x4 o = {(bf16)v.x, (bf16)v.y, (bf16)v.z, (bf16)v.w};
      *(bf16x4*)&wCat[(size_t)row * 5120 + 1024 + col] = o;
    }
  }
}

// ---------------- GEMM 256x256xBK64 core (m201-style 4-phase) ----------------
DEV bf16x8 ldfrag(const bf16* unit, int lr, int g) {
  return *(const bf16x8*)&unit[lr * 32 + ((g ^ ((lr >> 1) & 3)) << 3)];
}
DEV void read_bfr(const bf16* unit, int blr, int g, bf16x8 bfr[4]) {
  #pragma unroll
  for (int nj = 0; nj < 4; ++nj) bfr[nj] = ldfrag(unit, blr + nj * 16, g);
}
DEV void read_af(const bf16* unit, int alr, int g, bf16x8 af[4]) {
  #pragma unroll
  for (int ml = 0; ml < 4; ++ml) af[ml] = ldfrag(unit, alr + ml * 16, g);
}
DEV void do_mfma(const bf16x8 af[4], const bf16x8 bfr[4], f32x4 acc[8][4], int mh) {
  __builtin_amdgcn_s_setprio(1);
  #pragma unroll
  for (int ml = 0; ml < 4; ++ml)
    #pragma unroll
    for (int nj = 0; nj < 4; ++nj)
      acc[mh * 4 + ml][nj] = mfma16(af[ml], bfr[nj], acc[mh * 4 + ml][nj]);
  __builtin_amdgcn_s_setprio(0);
}

// K-loop shared by both GEMM kernels. As/Bs: [2][2][2][4096].
DEV void gemm_kloop(bf16 (*As)[2][2][4096], bf16 (*Bs)[2][2][4096],
                    const bf16* aU[2][2], const bf16* bU[2][2],
                    int wave, int alr, int blr, int bub, int g, int nkt,
                    f32x4 acc[8][4])
{
  bf16x8 bfr[4], af[4];
#define STG_A(bf_, kkh_, ub_, ko_) gload_lds16(aU[kkh_][ub_] + (ko_), &As[bf_][kkh_][ub_][wave * 512])
#define STG_B(bf_, kkh_, ub_, ko_) gload_lds16(bU[kkh_][ub_] + (ko_), &Bs[bf_][kkh_][ub_][wave * 512])
  STG_B(0, 0, 0, 0); STG_B(0, 0, 1, 0); STG_A(0, 0, 0, 0); STG_A(0, 0, 1, 0);
  STG_B(0, 1, 0, 0); STG_B(0, 1, 1, 0); STG_A(0, 1, 0, 0); STG_A(0, 1, 1, 0);
  WAITBAR("4");

  for (int t = 0; t < nkt - 1; ++t) {
    const int buf = t & 1, nxt = buf ^ 1;
    const int ko = (t + 1) * 64;
    read_bfr(&Bs[buf][0][bub][0], blr, g, bfr);
    read_af(&As[buf][0][0][0], alr, g, af);
    STG_B(nxt, 0, 0, ko); STG_B(nxt, 0, 1, ko);
    PH_BAR;
    do_mfma(af, bfr, acc, 0);
    PH_BAR;
    read_af(&As[buf][0][1][0], alr, g, af);
    STG_A(nxt, 0, 0, ko); STG_A(nxt, 0, 1, ko);
    PH_BAR;
    do_mfma(af, bfr, acc, 1);
    VM("4");
    PH_BAR;
    read_bfr(&Bs[buf][1][bub][0], blr, g, bfr);
    read_af(&As[buf][1][0][0], alr, g, af);
    STG_B(nxt, 1, 0, ko); STG_B(nxt, 1, 1, ko);
    PH_BAR;
    do_mfma(af, bfr, acc, 0);
    PH_BAR;
    read_af(&As[buf][1][1][0], alr, g, af);
    STG_A(nxt, 1, 0, ko); STG_A(nxt, 1, 1, ko);
    PH_BAR;
    do_mfma(af, bfr, acc, 1);
    VM("4");
    PH_BAR;
  }
  {
    const int buf = (nkt - 1) & 1;
    read_bfr(&Bs[buf][0][bub][0], blr, g, bfr);
    read_af(&As[buf][0][0][0], alr, g, af);
    PH_BAR;
    do_mfma(af, bfr, acc, 0);
    PH_BAR;
    read_af(&As[buf][0][1][0], alr, g, af);
    PH_BAR;
    do_mfma(af, bfr, acc, 1);
    VM("0");
    PH_BAR;
    read_bfr(&Bs[buf][1][bub][0], blr, g, bfr);
    read_af(&As[buf][1][0][0], alr, g, af);
    PH_BAR;
    do_mfma(af, bfr, acc, 0);
    PH_BAR;
    read_af(&As[buf][1][1][0], alr, g, af);
    PH_BAR;
    do_mfma(af, bfr, acc, 1);
  }
#undef STG_A
#undef STG_B
}

// ---- merged QKV + FF1 dispatch: blocks [0,192) QKV (bias), [192,448) FF1 (gelu)
__global__ __launch_bounds__(512) void gemm_dual(
    const bf16* __restrict__ A0, const bf16* __restrict__ B0,
    const float* __restrict__ bias0, bf16* __restrict__ C0,
    const bf16* __restrict__ A1, const bf16* __restrict__ B1,
    const float* __restrict__ bias1, bf16* __restrict__ C1)
{
  __shared__ __align__(16) bf16 As[2][2][2][4096];
  __shared__ __align__(16) bf16 Bs[2][2][2][4096];
  const int tid = threadIdx.x;
  const int lane = tid & 63, wave = tid >> 6;
  const int wm = wave >> 2, wn = wave & 3;
  const int g = lane >> 4, c = lane & 15;

  const int bid = blockIdx.x;
  const int seg = (bid >= 192);
  const int nseg = seg ? 256 : 192;
  const int nbx  = seg ? 16 : 12;
  const int ldc  = seg ? 5120 : 3072;
  const bf16* A = seg ? A1 : A0;
  const bf16* B = seg ? B1 : B0;
  const float* bias = seg ? bias1 : bias0;
  bf16* C = seg ? C1 : C0;
  const int K = 1024, nkt = 16;

  const int bs = bid - (seg ? 192 : 0);
  const int cpx = nseg >> 3;
  const int swz = (bs & 7) * cpx + (bs >> 3);
  const int bm = (swz / nbx) * 256, bn = (swz % nbx) * 256;

  const int slr = tid >> 2;
  const int sch = (tid & 3) ^ ((tid >> 3) & 3);
  const bf16* aU[2][2];
  const bf16* bU[2][2];
  {
    const bf16* a0 = A + (size_t)(bm + ((slr >> 6) * 128) + (slr & 63)) * K + sch * 8;
    const bf16* b0 = B + (size_t)(bn + slr) * K + sch * 8;
    aU[0][0] = a0;            aU[0][1] = a0 + (size_t)64 * K;
    aU[1][0] = a0 + 32;       aU[1][1] = a0 + (size_t)64 * K + 32;
    bU[0][0] = b0;            bU[0][1] = b0 + (size_t)128 * K;
    bU[1][0] = b0 + 32;       bU[1][1] = b0 + (size_t)128 * K + 32;
  }

  f32x4 acc[8][4] = {};
  const int alr = (wm << 6) + c;
  const int blr = ((wn & 1) << 6) + c;
  const int bub = wn >> 1;

  gemm_kloop(As, Bs, aU, bU, wave, alr, blr, bub, g, nkt, acc);

  const int row0 = bm + wm * 128 + 4 * g;
  const int col0 = bn + wn * 64 + c;
  #pragma unroll
  for (int mi = 0; mi < 8; ++mi) {
    #pragma unroll
    for (int nj = 0; nj < 4; ++nj) {
      const int col = col0 + nj * 16;
      const float bv = bias[col];
      #pragma unroll
      for (int r = 0; r < 4; ++r) {
        const size_t idx = (size_t)(row0 + mi * 16 + r) * ldc + col;
        const float vo = acc[mi][nj][r] + bv;
        C[idx] = (bf16)(seg ? fast_gelu(vo) : vo);
      }
    }
  }
}

// ---- fused Wo+FF2 split-K4 (bf16 partials)
__global__ __launch_bounds__(512) void gemm_splitk(
    const bf16* __restrict__ A, const bf16* __restrict__ B,
    bf16* __restrict__ P0, bf16* __restrict__ P1,
    bf16* __restrict__ P2, bf16* __restrict__ P3,
    int K, int ldc, int ntiles, int nbx, int nkt)
{
  __shared__ __align__(16) bf16 As[2][2][2][4096];
  __shared__ __align__(16) bf16 Bs[2][2][2][4096];
  const int tid = threadIdx.x;
  const int lane = tid & 63, wave = tid >> 6;
  const int wm = wave >> 2, wn = wave & 3;
  const int g = lane >> 4, c = lane & 15;
  const int cpx = gridDim.x >> 3;
  const int swz = ((int)blockIdx.x & 7) * cpx + ((int)blockIdx.x >> 3);
  const int tile = swz % ntiles;
  const int sk = swz / ntiles;
  const int bm = (tile / nbx) * 256, bn = (tile % nbx) * 256;

  const int slr = tid >> 2;
  const int sch = (tid & 3) ^ ((tid >> 3) & 3);
  const bf16* aU[2][2];
  const bf16* bU[2][2];
  {
    const bf16* a0 = A + (size_t)(bm + ((slr >> 6) * 128) + (slr & 63)) * K
                       + (size_t)sk * nkt * 64 + sch * 8;
    const bf16* b0 = B + (size_t)(bn + slr) * K + (size_t)sk * nkt * 64 + sch * 8;
    aU[0][0] = a0;            aU[0][1] = a0 + (size_t)64 * K;
    aU[1][0] = a0 + 32;       aU[1][1] = a0 + (size_t)64 * K + 32;
    bU[0][0] = b0;            bU[0][1] = b0 + (size_t)128 * K;
    bU[1][0] = b0 + 32;       bU[1][1] = b0 + (size_t)128 * K + 32;
  }

  f32x4 acc[8][4] = {};
  const int alr = (wm << 6) + c;
  const int blr = ((wn & 1) << 6) + c;
  const int bub = wn >> 1;

  gemm_kloop(As, Bs, aU, bU, wave, alr, blr, bub, g, nkt, acc);

  bf16* Pp = (sk == 1) ? P1 : (sk == 2) ? P2 : (sk == 3) ? P3 : P0;
  const int row0 = bm + wm * 128 + 4 * g;
  const int col0 = bn + wn * 64 + c;
  #pragma unroll
  for (int mi = 0; mi < 8; ++mi) {
    #pragma unroll
    for (int nj = 0; nj < 4; ++nj) {
      const int col = col0 + nj * 16;
      #pragma unroll
      for (int r = 0; r < 4; ++r) {
        const size_t idx = (size_t)(row0 + mi * 16 + r) * ldc + col;
        Pp[idx] = (bf16)acc[mi][nj][r];
      }
    }
  }
}

// ---------------- combine: out = q0+q1+q2+q3 + x + b_o + b2 ----------------
__global__ __launch_bounds__(256) void combine_out(
    const bf16* __restrict__ q0, const bf16* __restrict__ q1,
    const bf16* __restrict__ q2, const bf16* __restrict__ q3,
    const float* __restrict__ x,
    const float* __restrict__ bo, const float* __restrict__ b2,
    float* __restrict__ out)
{
  const int row = blockIdx.x, t = threadIdx.x;
  const size_t base = (size_t)row * 1024 + t * 4;
  const bf16x4 a0 = *(const bf16x4*)&q0[base];
  const bf16x4 a1 = *(const bf16x4*)&q1[base];
  const bf16x4 a2 = *(const bf16x4*)&q2[base];
  const bf16x4 a3 = *(const bf16x4*)&q3[base];
  const float4 vx = *(const float4*)&x[base];
  const float4 vb = *(const float4*)&bo[t * 4];
  const float4 vc = *(const float4*)&b2[t * 4];
  float4 o;
  o.x = (float)a0[0] + (float)a1[0] + (float)a2[0] + (float)a3[0] + vx.x + vb.x + vc.x;
  o.y = (float)a0[1] + (float)a1[1] + (float)a2[1] + (float)a3[1] + vx.y + vb.y + vc.y;
  o.z = (float)a0[2] + (float)a1[2] + (float)a2[2] + (float)a3[2] + vx.z + vb.z + vc.z;
  o.w = (float)a0[3] + (float)a1[3] + (float)a2[3] + (float)a3[3] + vx.w + vb.w + vc.w;
  *(float4*)&out[base] = o;
}

// ---------------- RoPE + head reshape; also writes V^T ----------------
__global__ __launch_bounds__(256) void rope_reshape(
    const bf16* __restrict__ qkv, const float* __restrict__ freqs,
    bf16* __restrict__ Q, bf16* __restrict__ K, bf16* __restrict__ VT)
{
  __shared__ bf16 vt[64][72];
  const int t = threadIdx.x;
  const int bh = blockIdx.y, b = bh >> 4, h = bh & 15;
  const int sc = blockIdx.x * 64;
  const int sl = t >> 2, s = sc + sl;
  const int d0 = (t & 3) * 16;

  const size_t rowbase = (size_t)(b * 2048 + s) * 3072 + h * 64 + d0;
  const size_t obase = ((size_t)bh * 2048 + s) * 64 + d0;

  #pragma unroll
  for (int which = 0; which < 2; ++which) {
    const bf16* src = qkv + rowbase + which * 1024;
    bf16x8 v0 = *(const bf16x8*)src;
    bf16x8 v1 = *(const bf16x8*)(src + 8);
    if (d0 == 0) {
      bf16x8 r0, r1;
      #pragma unroll
      for (int j = 0; j < 8; ++j) {
        const float cs = freqs[s * 16 + j * 2];
        const float sn = freqs[s * 16 + j * 2 + 1];
        const float x1 = (float)v0[j], x2 = (float)v1[j];
        r0[j] = (bf16)(x1 * cs - x2 * sn);
        r1[j] = (bf16)(x1 * sn + x2 * cs);
      }
      v0 = r0; v1 = r1;
    }
    bf16* dst = (which == 0 ? Q : K) + obase;
    *(bf16x8*)dst = v0;
    *(bf16x8*)(dst + 8) = v1;
  }
  {
    const bf16* src = qkv + rowbase + 2048;
    bf16x8 v0 = *(const bf16x8*)src;
    bf16x8 v1 = *(const bf16x8*)(src + 8);
    #pragma unroll
    for (int j = 0; j < 8; ++j) { vt[sl][d0 + j] = v0[j]; vt[sl][d0 + 8 + j] = v1[j]; }
  }
  __syncthreads();
  {
    const int d = t >> 2;
    const int s0 = (t & 3) * 16;
    bf16x8 o0, o1;
    #pragma unroll
    for (int j = 0; j < 8; ++j) { o0[j] = vt[s0 + j][d]; o1[j] = vt[s0 + 8 + j][d]; }
    bf16* dst = VT + ((size_t)bh * 64 + d) * 2048 + sc + s0;
    *(bf16x8*)dst = o0;
    *(bf16x8*)(dst + 8) = o1;
  }
}

// ---------------- Causal flash attention (v7) ----------------
// R12: QBLK=256, 1024 threads (16 waves = 4/SIMD), grid 256 = 1 block/CU —
// removes the 2-waves/SIMD phase after a light co-resident block exits
// (R11: Occupancy 23.6%). Staging splits K (tid<512) and V (tid>=512),
// 1 load/thread/tile, counted vmcnt(1). LDS = 4x8K K + 4x8K V + 32K Ps = 96KB.
__global__ __launch_bounds__(1024, 4) void attn_kernel(
    const bf16* __restrict__ Q, const bf16* __restrict__ Kg,
    const bf16* __restrict__ VTg, bf16* __restrict__ O, int ldO)
{
  __shared__ __align__(16) bf16 Ks[4][64][64];
  __shared__ __align__(16) bf16 Vs[4][64][64];
  __shared__ __align__(16) bf16 Ps[16][16][64];

  const int tid = threadIdx.x;
  const int lane = tid & 63, wave = tid >> 6;   // wave 0..15
  const int g = lane >> 4, c = lane & 15;
  const int L = blockIdx.x;
  const int bh = L >> 3, p = L & 7;             // 8 q-superblocks of 256 rows
  const int qw = p * 256 + wave * 16;

  const bf16* Qp = Q + (size_t)bh * 2048 * 64;
  const bf16* Kp = Kg + (size_t)bh * 2048 * 64;
  const bf16* Vp = VTg + (size_t)bh * 64 * 2048;

  // staging: tid<512 -> K, tid>=512 -> V; stage-wave stw 0..7 covers rows 8*stw..
  const int stw = (tid >> 6) & 7;
  const int srow = lane >> 3;
  const int schunk = (lane & 7) ^ srow;
  const int svr = stw * 8 + srow;
  const size_t kdelta = (size_t)64 * 64;

  bf16x8 qreg[2];
  {
    const float qs = 0.125f * 1.44269504f;
    bf16x8 t0 = *(const bf16x8*)&Qp[(size_t)(qw + c) * 64 + g * 8];
    bf16x8 t1 = *(const bf16x8*)&Qp[(size_t)(qw + c) * 64 + 32 + g * 8];
    #pragma unroll
    for (int j = 0; j < 8; ++j) {
      qreg[0][j] = (bf16)((float)t0[j] * qs);
      qreg[1][j] = (bf16)((float)t1[j] * qs);
    }
  }
  bf16x8 ones;
  #pragma unroll
  for (int j = 0; j < 8; ++j) ones[j] = (bf16)1.0f;

  const int cq = c & 7;
  int fo[4][2];
  #pragma unroll
  for (int i = 0; i < 4; ++i)
    #pragma unroll
    for (int kk = 0; kk < 2; ++kk)
      fo[i][kk] = (i * 16 + c) * 64 + (((kk * 4 + g) ^ cq) << 3);
  bf16* pw[4];
  #pragma unroll
  for (int kf = 0; kf < 4; ++kf)
    pw[kf] = &Ps[wave][c][((((kf * 2 + (g >> 1)) ^ cq) << 3)) + ((g & 1) << 2)];
  const bf16* pr[2];
  #pragma unroll
  for (int kk = 0; kk < 2; ++kk)
    pr[kk] = &Ps[wave][c][((kk * 4 + g) ^ cq) << 3];
  const bf16* ks0 = &Ks[0][0][0];
  const bf16* vs0 = &Vs[0][0][0];

  f32x4 oacc[4] = {};
  f32x4 lacc = {};
  float m_ = -1e30f;

  const int nkb = 4 * p + 4;  // even, >= 4
#define STAGE(j_) do { const int b4_ = (j_) & 3;                                     \
    if (tid < 512)                                                                   \
      gload_lds16(&Kp[(size_t)((j_) * 64 + svr) * 64 + schunk * 8], &Ks[b4_][stw * 8][0]); \
    else                                                                             \
      gload_lds16(&Vp[(size_t)svr * 2048 + (j_) * 64 + schunk * 8], &Vs[b4_][stw * 8][0]); \
  } while (0)

  auto qkt = [&](f32x4* st, int bufi) {
    const bf16* kt = ks0 + bufi * kdelta;
    __builtin_amdgcn_s_setprio(1);
    #pragma unroll
    for (int kf = 0; kf < 4; ++kf) {
      f32x4 z = {};
      z = mfma16(*(const bf16x8*)(kt + fo[kf][0]), qreg[0], z);
      st[kf] = mfma16(*(const bf16x8*)(kt + fo[kf][1]), qreg[1], z);
    }
    __builtin_amdgcn_s_setprio(0);
  };

  auto smpv = [&](const f32x4* st, int j_, int bufi) {
    const int kbase = j_ * 64;
    float v[16];
    if (kbase + 63 > qw) {
      const int qrel = qw + c - kbase;
      #pragma unroll
      for (int kf = 0; kf < 4; ++kf)
        #pragma unroll
        for (int rr = 0; rr < 4; ++rr)
          v[kf * 4 + rr] = (kf * 16 + 4 * g + rr <= qrel) ? st[kf][rr] : -1e30f;
    } else {
      #pragma unroll
      for (int kf = 0; kf < 4; ++kf)
        #pragma unroll
        for (int rr = 0; rr < 4; ++rr)
          v[kf * 4 + rr] = st[kf][rr];
    }
    float u0 = fmaxf(fmaxf(v[0], v[1]), v[2]);
    float u1 = fmaxf(fmaxf(v[3], v[4]), v[5]);
    float u2 = fmaxf(fmaxf(v[6], v[7]), v[8]);
    float u3 = fmaxf(fmaxf(v[9], v[10]), v[11]);
    float u4 = fmaxf(fmaxf(v[12], v[13]), v[14]);
    float tm = fmaxf(fmaxf(fmaxf(u0, u1), u2), fmaxf(fmaxf(u3, u4), v[15]));
    if (__any(tm > m_ + 8.0f)) {
      float tr = fmaxf(tm, __shfl_xor(tm, 16));
      tr = fmaxf(tr, __shfl_xor(tr, 32));
      const float mn = fmaxf(m_, tr);
      const float alpha = __builtin_amdgcn_exp2f(m_ - mn);
      m_ = mn;
      lacc[0] *= alpha; lacc[1] *= alpha; lacc[2] *= alpha; lacc[3] *= alpha;
      #pragma unroll
      for (int df = 0; df < 4; ++df) {
        oacc[df][0] *= alpha; oacc[df][1] *= alpha;
        oacc[df][2] *= alpha; oacc[df][3] *= alpha;
      }
    }
    bf16 pq[16];
    #pragma unroll
    for (int i = 0; i < 16; ++i)
      pq[i] = (bf16)__builtin_amdgcn_exp2f(v[i] - m_);
    #pragma unroll
    for (int kf = 0; kf < 4; ++kf) {
      bf16x4 pk = {pq[kf * 4], pq[kf * 4 + 1], pq[kf * 4 + 2], pq[kf * 4 + 3]};
      *(bf16x4*)pw[kf] = pk;
    }
    bf16x8 pfrag0 = *(const bf16x8*)pr[0];
    bf16x8 pfrag1 = *(const bf16x8*)pr[1];
    const bf16* vt = vs0 + bufi * kdelta;
    __builtin_amdgcn_s_setprio(1);
    #pragma unroll
    for (int df = 0; df < 4; ++df) {
      oacc[df] = mfma16(*(const bf16x8*)(vt + fo[df][0]), pfrag0, oacc[df]);
      oacc[df] = mfma16(*(const bf16x8*)(vt + fo[df][1]), pfrag1, oacc[df]);
    }
    lacc = mfma16(ones, pfrag0, lacc);
    lacc = mfma16(ones, pfrag1, lacc);
    __builtin_amdgcn_s_setprio(0);
  };

  f32x4 stA[4], stB[4];
  STAGE(0); STAGE(1); STAGE(2);
  VM("1");   // tiles 0,1 landed; S2 in flight
  PH_BAR;
  qkt(stA, 0);

  const int nit = nkb >> 1;
  for (int i = 0; i < nit; ++i) {
    const int jA = 2 * i, jB = 2 * i + 1;
    // ---- body A: consume tile jA (stA), prefetch QKT(jB)->stB, stage jA+3
    const bool stgA = (jA + 3 < nkb);
    if (stgA) STAGE(jA + 3);
    if (jB * 64 <= qw + 15) qkt(stB, jB & 3);
    if (jA * 64 <= qw + 15) smpv(stA, jA, jA & 3);
    if (stgA) { VM("1"); } else { VM("0"); }
    PH_BAR;
    // ---- body B: consume tile jB (stB), prefetch QKT(jB+1)->stA, stage jB+3
    const bool stgB = (jB + 3 < nkb);
    if (stgB) STAGE(jB + 3);
    if (jB + 1 < nkb && (jB + 1) * 64 <= qw + 15) qkt(stA, (jB + 1) & 3);
    if (jB * 64 <= qw + 15) smpv(stB, jB, jB & 3);
    if (stgB) { VM("1"); } else { VM("0"); }
    PH_BAR;
  }
#undef STAGE

  const int b = bh >> 4, h = bh & 15;
  const float inv = 1.0f / lacc[0];
  const int s = qw + c;
  #pragma unroll
  for (int df = 0; df < 4; ++df) {
    bf16x4 o;
    #pragma unroll
    for (int rr = 0; rr < 4; ++rr) o[rr] = (bf16)(oacc[df][rr] * inv);
    *(bf16x4*)&O[(size_t)(b * 2048 + s) * ldO + h * 64 + df * 16 + 4 * g] = o;
  }
}

// ---------------- host orchestration ----------------
extern "C" void kernel_launch(void* const* d_in, const int* in_sizes, int n_in,
                              void* d_out, int out_size, void* d_ws, size_t ws_size,
                              hipStream_t stream) {
  const float* x     = (const float*)d_in[0];
  const float* W_qkv = (const float*)d_in[2];
  const float* b_qkv = (const float*)d_in[3];
  const float* W_o   = (const float*)d_in[4];
  const float* b_o   = (const float*)d_in[5];
  const float* ln1w  = (const float*)d_in[6];
  const float* ln1b  = (const float*)d_in[7];
  const float* ln2w  = (const float*)d_in[8];
  const float* ln2b  = (const float*)d_in[9];
  const float* W1    = (const float*)d_in[10];
  const float* b1    = (const float*)d_in[11];
  const float* W2    = (const float*)d_in[12];
  const float* b2    = (const float*)d_in[13];
  const float* freqs = (const float*)d_in[14];
  float* out = (float*)d_out;

  char* ws = (char*)d_ws;
  const size_t MB = (size_t)1 << 20;
  bf16* h1   = (bf16*)(ws + 0 * MB);
  bf16* h2   = (bf16*)(ws + 8 * MB);
  bf16* wQKV = (bf16*)(ws + 16 * MB);
  bf16* wCat = (bf16*)(ws + 22 * MB);
  bf16* w1   = (bf16*)(ws + 32 * MB);
  bf16* qkv  = (bf16*)(ws + 40 * MB);
  bf16* Qb   = (bf16*)(ws + 64 * MB);
  bf16* Kb   = (bf16*)(ws + 72 * MB);
  bf16* VTb  = (bf16*)(ws + 80 * MB);
  bf16* A2   = (bf16*)(ws + 88 * MB);
  bf16* q0   = (bf16*)(ws + 0 * MB);
  bf16* q1   = (bf16*)(ws + 8 * MB);
  bf16* q2   = (bf16*)(ws + 40 * MB);
  bf16* q3   = (bf16*)(ws + 48 * MB);

  ln_cast_all<<<13312, 256, 0, stream>>>(x, ln1w, ln1b, ln2w, ln2b, h1, h2,
                                         W_qkv, W1, W_o, W2, wQKV, w1, wCat);
  // QKV (blocks 0..191) + FF1 (192..447) in one dispatch — both depend only on ln/cast
  gemm_dual<<<448, 512, 0, stream>>>(h1, wQKV, b_qkv, qkv,
                                     h2, w1, b1, A2 + 1024);
  rope_reshape<<<dim3(32, 32), 256, 0, stream>>>(qkv, freqs, Qb, Kb, VTb);
  attn_kernel<<<256, 1024, 0, stream>>>(Qb, Kb, VTb, A2, 5120);
  gemm_splitk<<<256, 512, 0, stream>>>(A2, wCat, q0, q1, q2, q3,
                                       5120, 1024, 64, 4, 20);
  combine_out<<<4096, 256, 0, stream>>>(q0, q1, q2, q3, x, b_o, b2, out);
}

// Round 13
// 202.143 us; speedup vs baseline: 1.0092x; 1.0092x over previous
//
#include <hip/hip_runtime.h>

#define DEV __device__ __forceinline__

typedef __bf16 bf16;
typedef bf16 bf16x4 __attribute__((ext_vector_type(4)));
typedef bf16 bf16x8 __attribute__((ext_vector_type(8)));
typedef float f32x4 __attribute__((ext_vector_type(4)));

DEV f32x4 mfma16(bf16x8 a, bf16x8 b, f32x4 c) {
  return __builtin_amdgcn_mfma_f32_16x16x32_bf16(a, b, c, 0, 0, 0);
}

DEV void gload_lds16(const bf16* g, bf16* l) {
  __builtin_amdgcn_global_load_lds((const __attribute__((address_space(1))) void*)g,
                                   (__attribute__((address_space(3))) void*)l, 16, 0, 0);
}

#define PH_BAR __builtin_amdgcn_s_barrier()
#define VM(NSTR) asm volatile("s_waitcnt vmcnt(" NSTR ")" ::: "memory")
#define WAITBAR(NSTR) asm volatile("s_waitcnt vmcnt(" NSTR ")\n\ts_barrier" ::: "memory")

// tanh-form GELU, exp2+rcp based (~8 VALU ops, overflow-safe both tails).
DEV float fast_gelu(float x) {
  const float z = x * x;
  const float w = __builtin_fmaf(z, 0.1029353f, 2.3019853f);
  const float e = __builtin_amdgcn_exp2f(x * w);
  const float r = __builtin_amdgcn_rcpf(1.0f + e);
  return x - x * r;
}

// ---------------- fused LayerNorm (rows) + all weight casts ----------------
__global__ __launch_bounds__(256) void ln_cast_all(
    const float* __restrict__ x,
    const float* __restrict__ ln1w, const float* __restrict__ ln1b,
    const float* __restrict__ ln2w, const float* __restrict__ ln2b,
    bf16* __restrict__ h1, bf16* __restrict__ h2,
    const float* __restrict__ Wqkv_f, const float* __restrict__ W1_f,
    const float* __restrict__ Wo_f, const float* __restrict__ W2_f,
    bf16* __restrict__ wQKV, bf16* __restrict__ w1, bf16* __restrict__ wCat)
{
  const int b = blockIdx.x, t = threadIdx.x;
  if (b < 4096) {
    __shared__ float red[2][4];
    const int lane = t & 63, wave = t >> 6;
    const float4 v = ((const float4*)(x + (size_t)b * 1024))[t];
    float vv[4] = {v.x, v.y, v.z, v.w};
    float s = vv[0] + vv[1] + vv[2] + vv[3];
    float q = vv[0]*vv[0] + vv[1]*vv[1] + vv[2]*vv[2] + vv[3]*vv[3];
    #pragma unroll
    for (int o = 32; o; o >>= 1) { s += __shfl_xor(s, o); q += __shfl_xor(q, o); }
    if (lane == 0) { red[0][wave] = s; red[1][wave] = q; }
    __syncthreads();
    s = red[0][0] + red[0][1] + red[0][2] + red[0][3];
    q = red[1][0] + red[1][1] + red[1][2] + red[1][3];
    const float mu = s * (1.0f / 1024.0f);
    const float var = q * (1.0f / 1024.0f) - mu * mu;
    const float rs = rsqrtf(var + 1e-5f);
    bf16x4 o1, o2;
    #pragma unroll
    for (int j = 0; j < 4; ++j) {
      const int i = t * 4 + j;
      const float xh = (vv[j] - mu) * rs;
      o1[j] = (bf16)(xh * ln1w[i] + ln1b[i]);
      o2[j] = (bf16)(xh * ln2w[i] + ln2b[i]);
    }
    *(bf16x4*)&h1[(size_t)b * 1024 + t * 4] = o1;
    *(bf16x4*)&h2[(size_t)b * 1024 + t * 4] = o2;
    return;
  }
  const int cb = b - 4096;
  if (cb < 3072) {
    const int i = cb * 256 + t;
    const float4 v = ((const float4*)Wqkv_f)[i];
    bf16x4 o = {(bf16)v.x, (bf16)v.y, (bf16)v.z, (bf16)v.w};
    ((bf16x4*)wQKV)[i] = o;
  } else if (cb < 7168) {
    const int i = (cb - 3072) * 256 + t;
    const float4 v = ((const float4*)W1_f)[i];
    bf16x4 o = {(bf16)v.x, (bf16)v.y, (bf16)v.z, (bf16)v.w};
    ((bf16x4*)w1)[i] = o;
  } else if (cb < 8192) {
    const int row = cb - 7168;
    const float4 v = *(const float4*)&Wo_f[(size_t)row * 1024 + t * 4];
    bf16x4 o = {(bf16)v.x, (bf16)v.y, (bf16)v.z, (bf16)v.w};
    *(bf16x4*)&wCat[(size_t)row * 5120 + t * 4] = o;
  } else {
    const int row = cb - 8192;
    #pragma unroll
    for (int k = 0; k < 4; ++k) {
      const int col = t * 4 + k * 1024;
      const float4 v = *(const float4*)&W2_f[(size_t)row * 4096 + col];
      bf16x4 o = {(bf16)v.x, (bf16)v.y, (bf16)v.z, (bf16)v.w};
      *(bf16x4*)&wCat[(size_t)row * 5120 + 1024 + col] = o;
    }
  }
}

// ---------------- GEMM 256x256xBK64 core (m201-style 4-phase) ----------------
DEV bf16x8 ldfrag(const bf16* unit, int lr, int g) {
  return *(const bf16x8*)&unit[lr * 32 + ((g ^ ((lr >> 1) & 3)) << 3)];
}
DEV void read_bfr(const bf16* unit, int blr, int g, bf16x8 bfr[4]) {
  #pragma unroll
  for (int nj = 0; nj < 4; ++nj) bfr[nj] = ldfrag(unit, blr + nj * 16, g);
}
DEV void read_af(const bf16* unit, int alr, int g, bf16x8 af[4]) {
  #pragma unroll
  for (int ml = 0; ml < 4; ++ml) af[ml] = ldfrag(unit, alr + ml * 16, g);
}
DEV void do_mfma(const bf16x8 af[4], const bf16x8 bfr[4], f32x4 acc[8][4], int mh) {
  __builtin_amdgcn_s_setprio(1);
  #pragma unroll
  for (int ml = 0; ml < 4; ++ml)
    #pragma unroll
    for (int nj = 0; nj < 4; ++nj)
      acc[mh * 4 + ml][nj] = mfma16(af[ml], bfr[nj], acc[mh * 4 + ml][nj]);
  __builtin_amdgcn_s_setprio(0);
}

// K-loop shared by all GEMM kernels. As/Bs: [2][2][2][4096].
DEV void gemm_kloop(bf16 (*As)[2][2][4096], bf16 (*Bs)[2][2][4096],
                    const bf16* aU[2][2], const bf16* bU[2][2],
                    int wave, int alr, int blr, int bub, int g, int nkt,
                    f32x4 acc[8][4])
{
  bf16x8 bfr[4], af[4];
#define STG_A(bf_, kkh_, ub_, ko_) gload_lds16(aU[kkh_][ub_] + (ko_), &As[bf_][kkh_][ub_][wave * 512])
#define STG_B(bf_, kkh_, ub_, ko_) gload_lds16(bU[kkh_][ub_] + (ko_), &Bs[bf_][kkh_][ub_][wave * 512])
  STG_B(0, 0, 0, 0); STG_B(0, 0, 1, 0); STG_A(0, 0, 0, 0); STG_A(0, 0, 1, 0);
  STG_B(0, 1, 0, 0); STG_B(0, 1, 1, 0); STG_A(0, 1, 0, 0); STG_A(0, 1, 1, 0);
  WAITBAR("4");

  for (int t = 0; t < nkt - 1; ++t) {
    const int buf = t & 1, nxt = buf ^ 1;
    const int ko = (t + 1) * 64;
    read_bfr(&Bs[buf][0][bub][0], blr, g, bfr);
    read_af(&As[buf][0][0][0], alr, g, af);
    STG_B(nxt, 0, 0, ko); STG_B(nxt, 0, 1, ko);
    PH_BAR;
    do_mfma(af, bfr, acc, 0);
    PH_BAR;
    read_af(&As[buf][0][1][0], alr, g, af);
    STG_A(nxt, 0, 0, ko); STG_A(nxt, 0, 1, ko);
    PH_BAR;
    do_mfma(af, bfr, acc, 1);
    VM("4");
    PH_BAR;
    read_bfr(&Bs[buf][1][bub][0], blr, g, bfr);
    read_af(&As[buf][1][0][0], alr, g, af);
    STG_B(nxt, 1, 0, ko); STG_B(nxt, 1, 1, ko);
    PH_BAR;
    do_mfma(af, bfr, acc, 0);
    PH_BAR;
    read_af(&As[buf][1][1][0], alr, g, af);
    STG_A(nxt, 1, 0, ko); STG_A(nxt, 1, 1, ko);
    PH_BAR;
    do_mfma(af, bfr, acc, 1);
    VM("4");
    PH_BAR;
  }
  {
    const int buf = (nkt - 1) & 1;
    read_bfr(&Bs[buf][0][bub][0], blr, g, bfr);
    read_af(&As[buf][0][0][0], alr, g, af);
    PH_BAR;
    do_mfma(af, bfr, acc, 0);
    PH_BAR;
    read_af(&As[buf][0][1][0], alr, g, af);
    PH_BAR;
    do_mfma(af, bfr, acc, 1);
    VM("0");
    PH_BAR;
    read_bfr(&Bs[buf][1][bub][0], blr, g, bfr);
    read_af(&As[buf][1][0][0], alr, g, af);
    PH_BAR;
    do_mfma(af, bfr, acc, 0);
    PH_BAR;
    read_af(&As[buf][1][1][0], alr, g, af);
    PH_BAR;
    do_mfma(af, bfr, acc, 1);
  }
#undef STG_A
#undef STG_B
}

// EPI: 0 = bf16 + bias; 1 = bf16 gelu(acc+bias); 2 = bf16 partial (split-K, no bias)
// Separate dispatches per GEMM: 128KB LDS => 1 block/CU, so any grid >256
// executes as 2+ sequential rounds (R12 merge: 448 blocks = 75us vs 51us split).
template <int EPI>
__global__ __launch_bounds__(512) void gemm256(
    const bf16* __restrict__ A, const bf16* __restrict__ B,
    const float* __restrict__ bias, void* __restrict__ Cv,
    void* __restrict__ P1, void* __restrict__ P2, void* __restrict__ P3,
    int K, int ldc, int ntiles, int nbx, int nkt)
{
  __shared__ __align__(16) bf16 As[2][2][2][4096];
  __shared__ __align__(16) bf16 Bs[2][2][2][4096];
  const int tid = threadIdx.x;
  const int lane = tid & 63, wave = tid >> 6;
  const int wm = wave >> 2, wn = wave & 3;
  const int g = lane >> 4, c = lane & 15;
  const int cpx = gridDim.x >> 3;
  const int swz = ((int)blockIdx.x & 7) * cpx + ((int)blockIdx.x >> 3);
  const int tile = swz % ntiles;
  const int sk = swz / ntiles;
  const int bm = (tile / nbx) * 256, bn = (tile % nbx) * 256;

  const int slr = tid >> 2;
  const int sch = (tid & 3) ^ ((tid >> 3) & 3);
  const bf16* aU[2][2];
  const bf16* bU[2][2];
  {
    const bf16* a0 = A + (size_t)(bm + ((slr >> 6) * 128) + (slr & 63)) * K
                       + (size_t)sk * nkt * 64 + sch * 8;
    const bf16* b0 = B + (size_t)(bn + slr) * K + (size_t)sk * nkt * 64 + sch * 8;
    aU[0][0] = a0;            aU[0][1] = a0 + (size_t)64 * K;
    aU[1][0] = a0 + 32;       aU[1][1] = a0 + (size_t)64 * K + 32;
    bU[0][0] = b0;            bU[0][1] = b0 + (size_t)128 * K;
    bU[1][0] = b0 + 32;       bU[1][1] = b0 + (size_t)128 * K + 32;
  }

  f32x4 acc[8][4] = {};
  const int alr = (wm << 6) + c;
  const int blr = ((wn & 1) << 6) + c;
  const int bub = wn >> 1;

  gemm_kloop(As, Bs, aU, bU, wave, alr, blr, bub, g, nkt, acc);

  bf16* Pp = nullptr;
  if constexpr (EPI == 2)
    Pp = (bf16*)((sk == 1) ? P1 : (sk == 2) ? P2 : (sk == 3) ? P3 : Cv);
  const int row0 = bm + wm * 128 + 4 * g;
  const int col0 = bn + wn * 64 + c;
  #pragma unroll
  for (int mi = 0; mi < 8; ++mi) {
    #pragma unroll
    for (int nj = 0; nj < 4; ++nj) {
      const int col = col0 + nj * 16;
      float bv = 0.0f;
      if constexpr (EPI < 2) bv = bias[col];
      #pragma unroll
      for (int r = 0; r < 4; ++r) {
        const size_t idx = (size_t)(row0 + mi * 16 + r) * ldc + col;
        float vo = acc[mi][nj][r] + bv;
        if constexpr (EPI == 0) {
          ((bf16*)Cv)[idx] = (bf16)vo;
        } else if constexpr (EPI == 1) {
          ((bf16*)Cv)[idx] = (bf16)fast_gelu(vo);
        } else {
          Pp[idx] = (bf16)vo;
        }
      }
    }
  }
}

// ---------------- combine: out = q0+q1+q2+q3 + x + b_o + b2 ----------------
__global__ __launch_bounds__(256) void combine_out(
    const bf16* __restrict__ q0, const bf16* __restrict__ q1,
    const bf16* __restrict__ q2, const bf16* __restrict__ q3,
    const float* __restrict__ x,
    const float* __restrict__ bo, const float* __restrict__ b2,
    float* __restrict__ out)
{
  const int row = blockIdx.x, t = threadIdx.x;
  const size_t base = (size_t)row * 1024 + t * 4;
  const bf16x4 a0 = *(const bf16x4*)&q0[base];
  const bf16x4 a1 = *(const bf16x4*)&q1[base];
  const bf16x4 a2 = *(const bf16x4*)&q2[base];
  const bf16x4 a3 = *(const bf16x4*)&q3[base];
  const float4 vx = *(const float4*)&x[base];
  const float4 vb = *(const float4*)&bo[t * 4];
  const float4 vc = *(const float4*)&b2[t * 4];
  float4 o;
  o.x = (float)a0[0] + (float)a1[0] + (float)a2[0] + (float)a3[0] + vx.x + vb.x + vc.x;
  o.y = (float)a0[1] + (float)a1[1] + (float)a2[1] + (float)a3[1] + vx.y + vb.y + vc.y;
  o.z = (float)a0[2] + (float)a1[2] + (float)a2[2] + (float)a3[2] + vx.z + vb.z + vc.z;
  o.w = (float)a0[3] + (float)a1[3] + (float)a2[3] + (float)a3[3] + vx.w + vb.w + vc.w;
  *(float4*)&out[base] = o;
}

// ---------------- RoPE + head reshape; also writes V^T ----------------
__global__ __launch_bounds__(256) void rope_reshape(
    const bf16* __restrict__ qkv, const float* __restrict__ freqs,
    bf16* __restrict__ Q, bf16* __restrict__ K, bf16* __restrict__ VT)
{
  __shared__ bf16 vt[64][72];
  const int t = threadIdx.x;
  const int bh = blockIdx.y, b = bh >> 4, h = bh & 15;
  const int sc = blockIdx.x * 64;
  const int sl = t >> 2, s = sc + sl;
  const int d0 = (t & 3) * 16;

  const size_t rowbase = (size_t)(b * 2048 + s) * 3072 + h * 64 + d0;
  const size_t obase = ((size_t)bh * 2048 + s) * 64 + d0;

  #pragma unroll
  for (int which = 0; which < 2; ++which) {
    const bf16* src = qkv + rowbase + which * 1024;
    bf16x8 v0 = *(const bf16x8*)src;
    bf16x8 v1 = *(const bf16x8*)(src + 8);
    if (d0 == 0) {
      bf16x8 r0, r1;
      #pragma unroll
      for (int j = 0; j < 8; ++j) {
        const float cs = freqs[s * 16 + j * 2];
        const float sn = freqs[s * 16 + j * 2 + 1];
        const float x1 = (float)v0[j], x2 = (float)v1[j];
        r0[j] = (bf16)(x1 * cs - x2 * sn);
        r1[j] = (bf16)(x1 * sn + x2 * cs);
      }
      v0 = r0; v1 = r1;
    }
    bf16* dst = (which == 0 ? Q : K) + obase;
    *(bf16x8*)dst = v0;
    *(bf16x8*)(dst + 8) = v1;
  }
  {
    const bf16* src = qkv + rowbase + 2048;
    bf16x8 v0 = *(const bf16x8*)src;
    bf16x8 v1 = *(const bf16x8*)(src + 8);
    #pragma unroll
    for (int j = 0; j < 8; ++j) { vt[sl][d0 + j] = v0[j]; vt[sl][d0 + 8 + j] = v1[j]; }
  }
  __syncthreads();
  {
    const int d = t >> 2;
    const int s0 = (t & 3) * 16;
    bf16x8 o0, o1;
    #pragma unroll
    for (int j = 0; j < 8; ++j) { o0[j] = vt[s0 + j][d]; o1[j] = vt[s0 + 8 + j][d]; }
    bf16* dst = VT + ((size_t)bh * 64 + d) * 2048 + sc + s0;
    *(bf16x8*)dst = o0;
    *(bf16x8*)(dst + 8) = o1;
  }
}

// ---------------- Causal flash attention (v7) ----------------
// QBLK=256, 1024 threads (16 waves = 4/SIMD), grid 256 = 1 block/CU.
// Staging splits K (tid<512) / V (tid>=512), 1 load/thread/tile, counted
// vmcnt(1). LDS = 4x8K K + 4x8K V + 32K Ps = 96KB.
__global__ __launch_bounds__(1024, 4) void attn_kernel(
    const bf16* __restrict__ Q, const bf16* __restrict__ Kg,
    const bf16* __restrict__ VTg, bf16* __restrict__ O, int ldO)
{
  __shared__ __align__(16) bf16 Ks[4][64][64];
  __shared__ __align__(16) bf16 Vs[4][64][64];
  __shared__ __align__(16) bf16 Ps[16][16][64];

  const int tid = threadIdx.x;
  const int lane = tid & 63, wave = tid >> 6;   // wave 0..15
  const int g = lane >> 4, c = lane & 15;
  const int L = blockIdx.x;
  const int bh = L >> 3, p = L & 7;             // 8 q-superblocks of 256 rows
  const int qw = p * 256 + wave * 16;

  const bf16* Qp = Q + (size_t)bh * 2048 * 64;
  const bf16* Kp = Kg + (size_t)bh * 2048 * 64;
  const bf16* Vp = VTg + (size_t)bh * 64 * 2048;

  const int stw = (tid >> 6) & 7;
  const int srow = lane >> 3;
  const int schunk = (lane & 7) ^ srow;
  const int svr = stw * 8 + srow;
  const size_t kdelta = (size_t)64 * 64;

  bf16x8 qreg[2];
  {
    const float qs = 0.125f * 1.44269504f;
    bf16x8 t0 = *(const bf16x8*)&Qp[(size_t)(qw + c) * 64 + g * 8];
    bf16x8 t1 = *(const bf16x8*)&Qp[(size_t)(qw + c) * 64 + 32 + g * 8];
    #pragma unroll
    for (int j = 0; j < 8; ++j) {
      qreg[0][j] = (bf16)((float)t0[j] * qs);
      qreg[1][j] = (bf16)((float)t1[j] * qs);
    }
  }
  bf16x8 ones;
  #pragma unroll
  for (int j = 0; j < 8; ++j) ones[j] = (bf16)1.0f;

  const int cq = c & 7;
  int fo[4][2];
  #pragma unroll
  for (int i = 0; i < 4; ++i)
    #pragma unroll
    for (int kk = 0; kk < 2; ++kk)
      fo[i][kk] = (i * 16 + c) * 64 + (((kk * 4 + g) ^ cq) << 3);
  bf16* pw[4];
  #pragma unroll
  for (int kf = 0; kf < 4; ++kf)
    pw[kf] = &Ps[wave][c][((((kf * 2 + (g >> 1)) ^ cq) << 3)) + ((g & 1) << 2)];
  const bf16* pr[2];
  #pragma unroll
  for (int kk = 0; kk < 2; ++kk)
    pr[kk] = &Ps[wave][c][((kk * 4 + g) ^ cq) << 3];
  const bf16* ks0 = &Ks[0][0][0];
  const bf16* vs0 = &Vs[0][0][0];

  f32x4 oacc[4] = {};
  f32x4 lacc = {};
  float m_ = -1e30f;

  const int nkb = 4 * p + 4;  // even, >= 4
#define STAGE(j_) do { const int b4_ = (j_) & 3;                                     \
    if (tid < 512)                                                                   \
      gload_lds16(&Kp[(size_t)((j_) * 64 + svr) * 64 + schunk * 8], &Ks[b4_][stw * 8][0]); \
    else                                                                             \
      gload_lds16(&Vp[(size_t)svr * 2048 + (j_) * 64 + schunk * 8], &Vs[b4_][stw * 8][0]); \
  } while (0)

  auto qkt = [&](f32x4* st, int bufi) {
    const bf16* kt = ks0 + bufi * kdelta;
    __builtin_amdgcn_s_setprio(1);
    #pragma unroll
    for (int kf = 0; kf < 4; ++kf) {
      f32x4 z = {};
      z = mfma16(*(const bf16x8*)(kt + fo[kf][0]), qreg[0], z);
      st[kf] = mfma16(*(const bf16x8*)(kt + fo[kf][1]), qreg[1], z);
    }
    __builtin_amdgcn_s_setprio(0);
  };

  auto smpv = [&](const f32x4* st, int j_, int bufi) {
    const int kbase = j_ * 64;
    float v[16];
    if (kbase + 63 > qw) {
      const int qrel = qw + c - kbase;
      #pragma unroll
      for (int kf = 0; kf < 4; ++kf)
        #pragma unroll
        for (int rr = 0; rr < 4; ++rr)
          v[kf * 4 + rr] = (kf * 16 + 4 * g + rr <= qrel) ? st[kf][rr] : -1e30f;
    } else {
      #pragma unroll
      for (int kf = 0; kf < 4; ++kf)
        #pragma unroll
        for (int rr = 0; rr < 4; ++rr)
          v[kf * 4 + rr] = st[kf][rr];
    }
    float u0 = fmaxf(fmaxf(v[0], v[1]), v[2]);
    float u1 = fmaxf(fmaxf(v[3], v[4]), v[5]);
    float u2 = fmaxf(fmaxf(v[6], v[7]), v[8]);
    float u3 = fmaxf(fmaxf(v[9], v[10]), v[11]);
    float u4 = fmaxf(fmaxf(v[12], v[13]), v[14]);
    float tm = fmaxf(fmaxf(fmaxf(u0, u1), u2), fmaxf(fmaxf(u3, u4), v[15]));
    if (__any(tm > m_ + 8.0f)) {
      float tr = fmaxf(tm, __shfl_xor(tm, 16));
      tr = fmaxf(tr, __shfl_xor(tr, 32));
      const float mn = fmaxf(m_, tr);
      const float alpha = __builtin_amdgcn_exp2f(m_ - mn);
      m_ = mn;
      lacc[0] *= alpha; lacc[1] *= alpha; lacc[2] *= alpha; lacc[3] *= alpha;
      #pragma unroll
      for (int df = 0; df < 4; ++df) {
        oacc[df][0] *= alpha; oacc[df][1] *= alpha;
        oacc[df][2] *= alpha; oacc[df][3] *= alpha;
      }
    }
    bf16 pq[16];
    #pragma unroll
    for (int i = 0; i < 16; ++i)
      pq[i] = (bf16)__builtin_amdgcn_exp2f(v[i] - m_);
    #pragma unroll
    for (int kf = 0; kf < 4; ++kf) {
      bf16x4 pk = {pq[kf * 4], pq[kf * 4 + 1], pq[kf * 4 + 2], pq[kf * 4 + 3]};
      *(bf16x4*)pw[kf] = pk;
    }
    bf16x8 pfrag0 = *(const bf16x8*)pr[0];
    bf16x8 pfrag1 = *(const bf16x8*)pr[1];
    const bf16* vt = vs0 + bufi * kdelta;
    __builtin_amdgcn_s_setprio(1);
    #pragma unroll
    for (int df = 0; df < 4; ++df) {
      oacc[df] = mfma16(*(const bf16x8*)(vt + fo[df][0]), pfrag0, oacc[df]);
      oacc[df] = mfma16(*(const bf16x8*)(vt + fo[df][1]), pfrag1, oacc[df]);
    }
    lacc = mfma16(ones, pfrag0, lacc);
    lacc = mfma16(ones, pfrag1, lacc);
    __builtin_amdgcn_s_setprio(0);
  };

  f32x4 stA[4], stB[4];
  STAGE(0); STAGE(1); STAGE(2);
  VM("1");   // tiles 0,1 landed; S2 in flight
  PH_BAR;
  qkt(stA, 0);

  const int nit = nkb >> 1;
  for (int i = 0; i < nit; ++i) {
    const int jA = 2 * i, jB = 2 * i + 1;
    const bool stgA = (jA + 3 < nkb);
    if (stgA) STAGE(jA + 3);
    if (jB * 64 <= qw + 15) qkt(stB, jB & 3);
    if (jA * 64 <= qw + 15) smpv(stA, jA, jA & 3);
    if (stgA) { VM("1"); } else { VM("0"); }
    PH_BAR;
    const bool stgB = (jB + 3 < nkb);
    if (stgB) STAGE(jB + 3);
    if (jB + 1 < nkb && (jB + 1) * 64 <= qw + 15) qkt(stA, (jB + 1) & 3);
    if (jB * 64 <= qw + 15) smpv(stB, jB, jB & 3);
    if (stgB) { VM("1"); } else { VM("0"); }
    PH_BAR;
  }
#undef STAGE

  const int b = bh >> 4, h = bh & 15;
  const float inv = 1.0f / lacc[0];
  const int s = qw + c;
  #pragma unroll
  for (int df = 0; df < 4; ++df) {
    bf16x4 o;
    #pragma unroll
    for (int rr = 0; rr < 4; ++rr) o[rr] = (bf16)(oacc[df][rr] * inv);
    *(bf16x4*)&O[(size_t)(b * 2048 + s) * ldO + h * 64 + df * 16 + 4 * g] = o;
  }
}

// ---------------- host orchestration ----------------
extern "C" void kernel_launch(void* const* d_in, const int* in_sizes, int n_in,
                              void* d_out, int out_size, void* d_ws, size_t ws_size,
                              hipStream_t stream) {
  const float* x     = (const float*)d_in[0];
  const float* W_qkv = (const float*)d_in[2];
  const float* b_qkv = (const float*)d_in[3];
  const float* W_o   = (const float*)d_in[4];
  const float* b_o   = (const float*)d_in[5];
  const float* ln1w  = (const float*)d_in[6];
  const float* ln1b  = (const float*)d_in[7];
  const float* ln2w  = (const float*)d_in[8];
  const float* ln2b  = (const float*)d_in[9];
  const float* W1    = (const float*)d_in[10];
  const float* b1    = (const float*)d_in[11];
  const float* W2    = (const float*)d_in[12];
  const float* b2    = (const float*)d_in[13];
  const float* freqs = (const float*)d_in[14];
  float* out = (float*)d_out;

  char* ws = (char*)d_ws;
  const size_t MB = (size_t)1 << 20;
  bf16* h1   = (bf16*)(ws + 0 * MB);
  bf16* h2   = (bf16*)(ws + 8 * MB);
  bf16* wQKV = (bf16*)(ws + 16 * MB);
  bf16* wCat = (bf16*)(ws + 22 * MB);
  bf16* w1   = (bf16*)(ws + 32 * MB);
  bf16* qkv  = (bf16*)(ws + 40 * MB);
  bf16* Qb   = (bf16*)(ws + 64 * MB);
  bf16* Kb   = (bf16*)(ws + 72 * MB);
  bf16* VTb  = (bf16*)(ws + 80 * MB);
  bf16* A2   = (bf16*)(ws + 88 * MB);
  bf16* q0   = (bf16*)(ws + 0 * MB);
  bf16* q1   = (bf16*)(ws + 8 * MB);
  bf16* q2   = (bf16*)(ws + 40 * MB);
  bf16* q3   = (bf16*)(ws + 48 * MB);

  ln_cast_all<<<13312, 256, 0, stream>>>(x, ln1w, ln1b, ln2w, ln2b, h1, h2,
                                         W_qkv, W1, W_o, W2, wQKV, w1, wCat);
  gemm256<0><<<192, 512, 0, stream>>>(h1, wQKV, b_qkv, qkv,
                                      nullptr, nullptr, nullptr,
                                      1024, 3072, 192, 12, 16);
  rope_reshape<<<dim3(32, 32), 256, 0, stream>>>(qkv, freqs, Qb, Kb, VTb);
  attn_kernel<<<256, 1024, 0, stream>>>(Qb, Kb, VTb, A2, 5120);
  gemm256<1><<<256, 512, 0, stream>>>(h2, w1, b1, A2 + 1024,
                                      nullptr, nullptr, nullptr,
                                      1024, 5120, 256, 16, 16);
  gemm256<2><<<256, 512, 0, stream>>>(A2, wCat, nullptr, q0,
                                      q1, q2, q3,
                                      5120, 1024, 64, 4, 20);
  combine_out<<<4096, 256, 0, stream>>>(q0, q1, q2, q3, x, b_o, b2, out);
}

// Round 14
// 195.434 us; speedup vs baseline: 1.0439x; 1.0343x over previous
//
#include <hip/hip_runtime.h>

#define DEV __device__ __forceinline__

typedef __bf16 bf16;
typedef bf16 bf16x4 __attribute__((ext_vector_type(4)));
typedef bf16 bf16x8 __attribute__((ext_vector_type(8)));
typedef float f32x4 __attribute__((ext_vector_type(4)));

DEV f32x4 mfma16(bf16x8 a, bf16x8 b, f32x4 c) {
  return __builtin_amdgcn_mfma_f32_16x16x32_bf16(a, b, c, 0, 0, 0);
}

DEV void gload_lds16(const bf16* g, bf16* l) {
  __builtin_amdgcn_global_load_lds((const __attribute__((address_space(1))) void*)g,
                                   (__attribute__((address_space(3))) void*)l, 16, 0, 0);
}

#define PH_BAR __builtin_amdgcn_s_barrier()
#define VM(NSTR) asm volatile("s_waitcnt vmcnt(" NSTR ")" ::: "memory")
#define WAITBAR(NSTR) asm volatile("s_waitcnt vmcnt(" NSTR ")\n\ts_barrier" ::: "memory")

// tanh-form GELU, exp2+rcp based (~8 VALU ops, overflow-safe both tails).
DEV float fast_gelu(float x) {
  const float z = x * x;
  const float w = __builtin_fmaf(z, 0.1029353f, 2.3019853f);
  const float e = __builtin_amdgcn_exp2f(x * w);
  const float r = __builtin_amdgcn_rcpf(1.0f + e);
  return x - x * r;
}

// ---------------- fused LayerNorm (rows) + all weight casts ----------------
__global__ __launch_bounds__(256) void ln_cast_all(
    const float* __restrict__ x,
    const float* __restrict__ ln1w, const float* __restrict__ ln1b,
    const float* __restrict__ ln2w, const float* __restrict__ ln2b,
    bf16* __restrict__ h1, bf16* __restrict__ h2,
    const float* __restrict__ Wqkv_f, const float* __restrict__ W1_f,
    const float* __restrict__ Wo_f, const float* __restrict__ W2_f,
    bf16* __restrict__ wQKV, bf16* __restrict__ w1, bf16* __restrict__ wCat)
{
  const int b = blockIdx.x, t = threadIdx.x;
  if (b < 4096) {
    __shared__ float red[2][4];
    const int lane = t & 63, wave = t >> 6;
    const float4 v = ((const float4*)(x + (size_t)b * 1024))[t];
    float vv[4] = {v.x, v.y, v.z, v.w};
    float s = vv[0] + vv[1] + vv[2] + vv[3];
    float q = vv[0]*vv[0] + vv[1]*vv[1] + vv[2]*vv[2] + vv[3]*vv[3];
    #pragma unroll
    for (int o = 32; o; o >>= 1) { s += __shfl_xor(s, o); q += __shfl_xor(q, o); }
    if (lane == 0) { red[0][wave] = s; red[1][wave] = q; }
    __syncthreads();
    s = red[0][0] + red[0][1] + red[0][2] + red[0][3];
    q = red[1][0] + red[1][1] + red[1][2] + red[1][3];
    const float mu = s * (1.0f / 1024.0f);
    const float var = q * (1.0f / 1024.0f) - mu * mu;
    const float rs = rsqrtf(var + 1e-5f);
    bf16x4 o1, o2;
    #pragma unroll
    for (int j = 0; j < 4; ++j) {
      const int i = t * 4 + j;
      const float xh = (vv[j] - mu) * rs;
      o1[j] = (bf16)(xh * ln1w[i] + ln1b[i]);
      o2[j] = (bf16)(xh * ln2w[i] + ln2b[i]);
    }
    *(bf16x4*)&h1[(size_t)b * 1024 + t * 4] = o1;
    *(bf16x4*)&h2[(size_t)b * 1024 + t * 4] = o2;
    return;
  }
  const int cb = b - 4096;
  if (cb < 3072) {
    const int i = cb * 256 + t;
    const float4 v = ((const float4*)Wqkv_f)[i];
    bf16x4 o = {(bf16)v.x, (bf16)v.y, (bf16)v.z, (bf16)v.w};
    ((bf16x4*)wQKV)[i] = o;
  } else if (cb < 7168) {
    const int i = (cb - 3072) * 256 + t;
    const float4 v = ((const float4*)W1_f)[i];
    bf16x4 o = {(bf16)v.x, (bf16)v.y, (bf16)v.z, (bf16)v.w};
    ((bf16x4*)w1)[i] = o;
  } else if (cb < 8192) {
    const int row = cb - 7168;
    const float4 v = *(const float4*)&Wo_f[(size_t)row * 1024 + t * 4];
    bf16x4 o = {(bf16)v.x, (bf16)v.y, (bf16)v.z, (bf16)v.w};
    *(bf16x4*)&wCat[(size_t)row * 5120 + t * 4] = o;
  } else {
    const int row = cb - 8192;
    #pragma unroll
    for (int k = 0; k < 4; ++k) {
      const int col = t * 4 + k * 1024;
      const float4 v = *(const float4*)&W2_f[(size_t)row * 4096 + col];
      bf16x4 o = {(bf16)v.x, (bf16)v.y, (bf16)v.z, (bf16)v.w};
      *(bf16x4*)&wCat[(size_t)row * 5120 + 1024 + col] = o;
    }
  }
}

// ---------------- GEMM 256x256xBK64 core (m201-style 4-phase) ----------------
DEV bf16x8 ldfrag(const bf16* unit, int lr, int g) {
  return *(const bf16x8*)&unit[lr * 32 + ((g ^ ((lr >> 1) & 3)) << 3)];
}
DEV void read_bfr(const bf16* unit, int blr, int g, bf16x8 bfr[4]) {
  #pragma unroll
  for (int nj = 0; nj < 4; ++nj) bfr[nj] = ldfrag(unit, blr + nj * 16, g);
}
DEV void read_af(const bf16* unit, int alr, int g, bf16x8 af[4]) {
  #pragma unroll
  for (int ml = 0; ml < 4; ++ml) af[ml] = ldfrag(unit, alr + ml * 16, g);
}
DEV void do_mfma(const bf16x8 af[4], const bf16x8 bfr[4], f32x4 acc[8][4], int mh) {
  __builtin_amdgcn_s_setprio(1);
  #pragma unroll
  for (int ml = 0; ml < 4; ++ml)
    #pragma unroll
    for (int nj = 0; nj < 4; ++nj)
      acc[mh * 4 + ml][nj] = mfma16(af[ml], bfr[nj], acc[mh * 4 + ml][nj]);
  __builtin_amdgcn_s_setprio(0);
}

// K-loop shared by all GEMM kernels. As/Bs: [2][2][2][4096].
DEV void gemm_kloop(bf16 (*As)[2][2][4096], bf16 (*Bs)[2][2][4096],
                    const bf16* aU[2][2], const bf16* bU[2][2],
                    int wave, int alr, int blr, int bub, int g, int nkt,
                    f32x4 acc[8][4])
{
  bf16x8 bfr[4], af[4];
#define STG_A(bf_, kkh_, ub_, ko_) gload_lds16(aU[kkh_][ub_] + (ko_), &As[bf_][kkh_][ub_][wave * 512])
#define STG_B(bf_, kkh_, ub_, ko_) gload_lds16(bU[kkh_][ub_] + (ko_), &Bs[bf_][kkh_][ub_][wave * 512])
  STG_B(0, 0, 0, 0); STG_B(0, 0, 1, 0); STG_A(0, 0, 0, 0); STG_A(0, 0, 1, 0);
  STG_B(0, 1, 0, 0); STG_B(0, 1, 1, 0); STG_A(0, 1, 0, 0); STG_A(0, 1, 1, 0);
  WAITBAR("4");

  for (int t = 0; t < nkt - 1; ++t) {
    const int buf = t & 1, nxt = buf ^ 1;
    const int ko = (t + 1) * 64;
    read_bfr(&Bs[buf][0][bub][0], blr, g, bfr);
    read_af(&As[buf][0][0][0], alr, g, af);
    STG_B(nxt, 0, 0, ko); STG_B(nxt, 0, 1, ko);
    PH_BAR;
    do_mfma(af, bfr, acc, 0);
    PH_BAR;
    read_af(&As[buf][0][1][0], alr, g, af);
    STG_A(nxt, 0, 0, ko); STG_A(nxt, 0, 1, ko);
    PH_BAR;
    do_mfma(af, bfr, acc, 1);
    VM("4");
    PH_BAR;
    read_bfr(&Bs[buf][1][bub][0], blr, g, bfr);
    read_af(&As[buf][1][0][0], alr, g, af);
    STG_B(nxt, 1, 0, ko); STG_B(nxt, 1, 1, ko);
    PH_BAR;
    do_mfma(af, bfr, acc, 0);
    PH_BAR;
    read_af(&As[buf][1][1][0], alr, g, af);
    STG_A(nxt, 1, 0, ko); STG_A(nxt, 1, 1, ko);
    PH_BAR;
    do_mfma(af, bfr, acc, 1);
    VM("4");
    PH_BAR;
  }
  {
    const int buf = (nkt - 1) & 1;
    read_bfr(&Bs[buf][0][bub][0], blr, g, bfr);
    read_af(&As[buf][0][0][0], alr, g, af);
    PH_BAR;
    do_mfma(af, bfr, acc, 0);
    PH_BAR;
    read_af(&As[buf][0][1][0], alr, g, af);
    PH_BAR;
    do_mfma(af, bfr, acc, 1);
    VM("0");
    PH_BAR;
    read_bfr(&Bs[buf][1][bub][0], blr, g, bfr);
    read_af(&As[buf][1][0][0], alr, g, af);
    PH_BAR;
    do_mfma(af, bfr, acc, 0);
    PH_BAR;
    read_af(&As[buf][1][1][0], alr, g, af);
    PH_BAR;
    do_mfma(af, bfr, acc, 1);
  }
#undef STG_A
#undef STG_B
}

// EPI: 0 = bf16 + bias; 1 = bf16 gelu(acc+bias); 2 = bf16 partial (split-K, no bias)
template <int EPI>
__global__ __launch_bounds__(512) void gemm256(
    const bf16* __restrict__ A, const bf16* __restrict__ B,
    const float* __restrict__ bias, void* __restrict__ Cv,
    void* __restrict__ P1, void* __restrict__ P2, void* __restrict__ P3,
    int K, int ldc, int ntiles, int nbx, int nkt)
{
  __shared__ __align__(16) bf16 As[2][2][2][4096];
  __shared__ __align__(16) bf16 Bs[2][2][2][4096];
  const int tid = threadIdx.x;
  const int lane = tid & 63, wave = tid >> 6;
  const int wm = wave >> 2, wn = wave & 3;
  const int g = lane >> 4, c = lane & 15;
  const int cpx = gridDim.x >> 3;
  const int swz = ((int)blockIdx.x & 7) * cpx + ((int)blockIdx.x >> 3);
  const int tile = swz % ntiles;
  const int sk = swz / ntiles;
  const int bm = (tile / nbx) * 256, bn = (tile % nbx) * 256;

  const int slr = tid >> 2;
  const int sch = (tid & 3) ^ ((tid >> 3) & 3);
  const bf16* aU[2][2];
  const bf16* bU[2][2];
  {
    const bf16* a0 = A + (size_t)(bm + ((slr >> 6) * 128) + (slr & 63)) * K
                       + (size_t)sk * nkt * 64 + sch * 8;
    const bf16* b0 = B + (size_t)(bn + slr) * K + (size_t)sk * nkt * 64 + sch * 8;
    aU[0][0] = a0;            aU[0][1] = a0 + (size_t)64 * K;
    aU[1][0] = a0 + 32;       aU[1][1] = a0 + (size_t)64 * K + 32;
    bU[0][0] = b0;            bU[0][1] = b0 + (size_t)128 * K;
    bU[1][0] = b0 + 32;       bU[1][1] = b0 + (size_t)128 * K + 32;
  }

  f32x4 acc[8][4] = {};
  const int alr = (wm << 6) + c;
  const int blr = ((wn & 1) << 6) + c;
  const int bub = wn >> 1;

  gemm_kloop(As, Bs, aU, bU, wave, alr, blr, bub, g, nkt, acc);

  bf16* Pp = nullptr;
  if constexpr (EPI == 2)
    Pp = (bf16*)((sk == 1) ? P1 : (sk == 2) ? P2 : (sk == 3) ? P3 : Cv);
  const int row0 = bm + wm * 128 + 4 * g;
  const int col0 = bn + wn * 64 + c;
  #pragma unroll
  for (int mi = 0; mi < 8; ++mi) {
    #pragma unroll
    for (int nj = 0; nj < 4; ++nj) {
      const int col = col0 + nj * 16;
      float bv = 0.0f;
      if constexpr (EPI < 2) bv = bias[col];
      #pragma unroll
      for (int r = 0; r < 4; ++r) {
        const size_t idx = (size_t)(row0 + mi * 16 + r) * ldc + col;
        float vo = acc[mi][nj][r] + bv;
        if constexpr (EPI == 0) {
          ((bf16*)Cv)[idx] = (bf16)vo;
        } else if constexpr (EPI == 1) {
          ((bf16*)Cv)[idx] = (bf16)fast_gelu(vo);
        } else {
          Pp[idx] = (bf16)vo;
        }
      }
    }
  }
}

// ---------------- combine: out = q0+q1+q2+q3 + x + b_o + b2 ----------------
__global__ __launch_bounds__(256) void combine_out(
    const bf16* __restrict__ q0, const bf16* __restrict__ q1,
    const bf16* __restrict__ q2, const bf16* __restrict__ q3,
    const float* __restrict__ x,
    const float* __restrict__ bo, const float* __restrict__ b2,
    float* __restrict__ out)
{
  const int row = blockIdx.x, t = threadIdx.x;
  const size_t base = (size_t)row * 1024 + t * 4;
  const bf16x4 a0 = *(const bf16x4*)&q0[base];
  const bf16x4 a1 = *(const bf16x4*)&q1[base];
  const bf16x4 a2 = *(const bf16x4*)&q2[base];
  const bf16x4 a3 = *(const bf16x4*)&q3[base];
  const float4 vx = *(const float4*)&x[base];
  const float4 vb = *(const float4*)&bo[t * 4];
  const float4 vc = *(const float4*)&b2[t * 4];
  float4 o;
  o.x = (float)a0[0] + (float)a1[0] + (float)a2[0] + (float)a3[0] + vx.x + vb.x + vc.x;
  o.y = (float)a0[1] + (float)a1[1] + (float)a2[1] + (float)a3[1] + vx.y + vb.y + vc.y;
  o.z = (float)a0[2] + (float)a1[2] + (float)a2[2] + (float)a3[2] + vx.z + vb.z + vc.z;
  o.w = (float)a0[3] + (float)a1[3] + (float)a2[3] + (float)a3[3] + vx.w + vb.w + vc.w;
  *(float4*)&out[base] = o;
}

// ---------------- RoPE + head reshape; also writes V^T ----------------
__global__ __launch_bounds__(256) void rope_reshape(
    const bf16* __restrict__ qkv, const float* __restrict__ freqs,
    bf16* __restrict__ Q, bf16* __restrict__ K, bf16* __restrict__ VT)
{
  __shared__ bf16 vt[64][72];
  const int t = threadIdx.x;
  const int bh = blockIdx.y, b = bh >> 4, h = bh & 15;
  const int sc = blockIdx.x * 64;
  const int sl = t >> 2, s = sc + sl;
  const int d0 = (t & 3) * 16;

  const size_t rowbase = (size_t)(b * 2048 + s) * 3072 + h * 64 + d0;
  const size_t obase = ((size_t)bh * 2048 + s) * 64 + d0;

  #pragma unroll
  for (int which = 0; which < 2; ++which) {
    const bf16* src = qkv + rowbase + which * 1024;
    bf16x8 v0 = *(const bf16x8*)src;
    bf16x8 v1 = *(const bf16x8*)(src + 8);
    if (d0 == 0) {
      bf16x8 r0, r1;
      #pragma unroll
      for (int j = 0; j < 8; ++j) {
        const float cs = freqs[s * 16 + j * 2];
        const float sn = freqs[s * 16 + j * 2 + 1];
        const float x1 = (float)v0[j], x2 = (float)v1[j];
        r0[j] = (bf16)(x1 * cs - x2 * sn);
        r1[j] = (bf16)(x1 * sn + x2 * cs);
      }
      v0 = r0; v1 = r1;
    }
    bf16* dst = (which == 0 ? Q : K) + obase;
    *(bf16x8*)dst = v0;
    *(bf16x8*)(dst + 8) = v1;
  }
  {
    const bf16* src = qkv + rowbase + 2048;
    bf16x8 v0 = *(const bf16x8*)src;
    bf16x8 v1 = *(const bf16x8*)(src + 8);
    #pragma unroll
    for (int j = 0; j < 8; ++j) { vt[sl][d0 + j] = v0[j]; vt[sl][d0 + 8 + j] = v1[j]; }
  }
  __syncthreads();
  {
    const int d = t >> 2;
    const int s0 = (t & 3) * 16;
    bf16x8 o0, o1;
    #pragma unroll
    for (int j = 0; j < 8; ++j) { o0[j] = vt[s0 + j][d]; o1[j] = vt[s0 + 8 + j][d]; }
    bf16* dst = VT + ((size_t)bh * 64 + d) * 2048 + sc + s0;
    *(bf16x8*)dst = o0;
    *(bf16x8*)(dst + 8) = o1;
  }
}

// ---------------- Causal flash attention (v6b) ----------------
// v6 structure (R11, measured 46.5us): QBLK=128, 512 thr, 4-buffer K/V,
// counted vmcnt(2), qkt-ahead pipeline. R14 change: SAME-BH complementary
// pairing — block L<256 -> (bh=L>>3, qt=8+(L&7)) heavy; L>=256 ->
// (bh=(L-256)>>3, qt=7-((L-256)&7)) light. CU c hosts blocks c and c+256:
// same bh, qt t and 15-t (uniform 34 units) AND identical K/V streams ->
// L2 hits; an XCD's 32 consecutive blocks span only 4 bh (2MB K/V <= L2).
__global__ __launch_bounds__(512, 4) void attn_kernel(
    const bf16* __restrict__ Q, const bf16* __restrict__ Kg,
    const bf16* __restrict__ VTg, bf16* __restrict__ O, int ldO)
{
  __shared__ __align__(16) bf16 Ks[4][64][64];
  __shared__ __align__(16) bf16 Vs[4][64][64];
  __shared__ __align__(16) bf16 Ps[8][16][64];

  const int tid = threadIdx.x;
  const int lane = tid & 63, wave = tid >> 6;
  const int g = lane >> 4, c = lane & 15;
  const int L = blockIdx.x;
  const int heavy = (L < 256);
  const int r = heavy ? L : (L - 256);
  const int bh = r >> 3;
  const int qtile = heavy ? (8 + (r & 7)) : (7 - (r & 7));
  const int qw = qtile * 128 + wave * 16;

  const bf16* Qp = Q + (size_t)bh * 2048 * 64;
  const bf16* Kp = Kg + (size_t)bh * 2048 * 64;
  const bf16* Vp = VTg + (size_t)bh * 64 * 2048;

  const int srow = lane >> 3;
  const int schunk = (lane & 7) ^ srow;
  const int svr = wave * 8 + srow;
  const size_t kdelta = (size_t)64 * 64;

  bf16x8 qreg[2];
  {
    const float qs = 0.125f * 1.44269504f;
    bf16x8 t0 = *(const bf16x8*)&Qp[(size_t)(qw + c) * 64 + g * 8];
    bf16x8 t1 = *(const bf16x8*)&Qp[(size_t)(qw + c) * 64 + 32 + g * 8];
    #pragma unroll
    for (int j = 0; j < 8; ++j) {
      qreg[0][j] = (bf16)((float)t0[j] * qs);
      qreg[1][j] = (bf16)((float)t1[j] * qs);
    }
  }
  bf16x8 ones;
  #pragma unroll
  for (int j = 0; j < 8; ++j) ones[j] = (bf16)1.0f;

  const int cq = c & 7;
  int fo[4][2];
  #pragma unroll
  for (int i = 0; i < 4; ++i)
    #pragma unroll
    for (int kk = 0; kk < 2; ++kk)
      fo[i][kk] = (i * 16 + c) * 64 + (((kk * 4 + g) ^ cq) << 3);
  bf16* pw[4];
  #pragma unroll
  for (int kf = 0; kf < 4; ++kf)
    pw[kf] = &Ps[wave][c][((((kf * 2 + (g >> 1)) ^ cq) << 3)) + ((g & 1) << 2)];
  const bf16* pr[2];
  #pragma unroll
  for (int kk = 0; kk < 2; ++kk)
    pr[kk] = &Ps[wave][c][((kk * 4 + g) ^ cq) << 3];
  const bf16* ks0 = &Ks[0][0][0];
  const bf16* vs0 = &Vs[0][0][0];

  f32x4 oacc[4] = {};
  f32x4 lacc = {};
  float m_ = -1e30f;

  const int nkb = 2 * qtile + 2;  // even, >= 2
#define STAGE(j_) do { const int b4_ = (j_) & 3;                                     \
    gload_lds16(&Kp[(size_t)((j_) * 64 + svr) * 64 + schunk * 8], &Ks[b4_][wave * 8][0]); \
    gload_lds16(&Vp[(size_t)svr * 2048 + (j_) * 64 + schunk * 8], &Vs[b4_][wave * 8][0]); \
  } while (0)

  auto qkt = [&](f32x4* st, int bufi) {
    const bf16* kt = ks0 + bufi * kdelta;
    __builtin_amdgcn_s_setprio(1);
    #pragma unroll
    for (int kf = 0; kf < 4; ++kf) {
      f32x4 z = {};
      z = mfma16(*(const bf16x8*)(kt + fo[kf][0]), qreg[0], z);
      st[kf] = mfma16(*(const bf16x8*)(kt + fo[kf][1]), qreg[1], z);
    }
    __builtin_amdgcn_s_setprio(0);
  };

  auto smpv = [&](const f32x4* st, int j_, int bufi) {
    const int kbase = j_ * 64;
    float v[16];
    if (kbase + 63 > qw) {
      const int qrel = qw + c - kbase;
      #pragma unroll
      for (int kf = 0; kf < 4; ++kf)
        #pragma unroll
        for (int rr = 0; rr < 4; ++rr)
          v[kf * 4 + rr] = (kf * 16 + 4 * g + rr <= qrel) ? st[kf][rr] : -1e30f;
    } else {
      #pragma unroll
      for (int kf = 0; kf < 4; ++kf)
        #pragma unroll
        for (int rr = 0; rr < 4; ++rr)
          v[kf * 4 + rr] = st[kf][rr];
    }
    float u0 = fmaxf(fmaxf(v[0], v[1]), v[2]);
    float u1 = fmaxf(fmaxf(v[3], v[4]), v[5]);
    float u2 = fmaxf(fmaxf(v[6], v[7]), v[8]);
    float u3 = fmaxf(fmaxf(v[9], v[10]), v[11]);
    float u4 = fmaxf(fmaxf(v[12], v[13]), v[14]);
    float tm = fmaxf(fmaxf(fmaxf(u0, u1), u2), fmaxf(fmaxf(u3, u4), v[15]));
    if (__any(tm > m_ + 8.0f)) {
      float tr = fmaxf(tm, __shfl_xor(tm, 16));
      tr = fmaxf(tr, __shfl_xor(tr, 32));
      const float mn = fmaxf(m_, tr);
      const float alpha = __builtin_amdgcn_exp2f(m_ - mn);
      m_ = mn;
      lacc[0] *= alpha; lacc[1] *= alpha; lacc[2] *= alpha; lacc[3] *= alpha;
      #pragma unroll
      for (int df = 0; df < 4; ++df) {
        oacc[df][0] *= alpha; oacc[df][1] *= alpha;
        oacc[df][2] *= alpha; oacc[df][3] *= alpha;
      }
    }
    bf16 pq[16];
    #pragma unroll
    for (int i = 0; i < 16; ++i)
      pq[i] = (bf16)__builtin_amdgcn_exp2f(v[i] - m_);
    #pragma unroll
    for (int kf = 0; kf < 4; ++kf) {
      bf16x4 pk = {pq[kf * 4], pq[kf * 4 + 1], pq[kf * 4 + 2], pq[kf * 4 + 3]};
      *(bf16x4*)pw[kf] = pk;
    }
    bf16x8 pfrag0 = *(const bf16x8*)pr[0];
    bf16x8 pfrag1 = *(const bf16x8*)pr[1];
    const bf16* vt = vs0 + bufi * kdelta;
    __builtin_amdgcn_s_setprio(1);
    #pragma unroll
    for (int df = 0; df < 4; ++df) {
      oacc[df] = mfma16(*(const bf16x8*)(vt + fo[df][0]), pfrag0, oacc[df]);
      oacc[df] = mfma16(*(const bf16x8*)(vt + fo[df][1]), pfrag1, oacc[df]);
    }
    lacc = mfma16(ones, pfrag0, lacc);
    lacc = mfma16(ones, pfrag1, lacc);
    __builtin_amdgcn_s_setprio(0);
  };

  f32x4 stA[4], stB[4];
  STAGE(0); STAGE(1); STAGE(2);
  VM("2");   // S0,S1 drained; S2 in flight
  PH_BAR;
  qkt(stA, 0);

  const int nit = nkb >> 1;
  for (int i = 0; i < nit; ++i) {
    const int jA = 2 * i, jB = 2 * i + 1;
    const bool stgA = (jA + 3 < nkb);
    if (stgA) STAGE(jA + 3);
    if (jB * 64 <= qw + 15) qkt(stB, jB & 3);
    smpv(stA, jA, jA & 3);
    if (stgA) { VM("2"); } else { VM("0"); }
    PH_BAR;
    const bool stgB = (jB + 3 < nkb);
    if (stgB) STAGE(jB + 3);
    if (jB + 1 < nkb && (jB + 1) * 64 <= qw + 15) qkt(stA, (jB + 1) & 3);
    if (jB * 64 <= qw + 15) smpv(stB, jB, jB & 3);
    if (stgB) { VM("2"); } else { VM("0"); }
    PH_BAR;
  }
#undef STAGE

  const int b = bh >> 4, h = bh & 15;
  const float inv = 1.0f / lacc[0];
  const int s = qw + c;
  #pragma unroll
  for (int df = 0; df < 4; ++df) {
    bf16x4 o;
    #pragma unroll
    for (int rr = 0; rr < 4; ++rr) o[rr] = (bf16)(oacc[df][rr] * inv);
    *(bf16x4*)&O[(size_t)(b * 2048 + s) * ldO + h * 64 + df * 16 + 4 * g] = o;
  }
}

// ---------------- host orchestration ----------------
extern "C" void kernel_launch(void* const* d_in, const int* in_sizes, int n_in,
                              void* d_out, int out_size, void* d_ws, size_t ws_size,
                              hipStream_t stream) {
  const float* x     = (const float*)d_in[0];
  const float* W_qkv = (const float*)d_in[2];
  const float* b_qkv = (const float*)d_in[3];
  const float* W_o   = (const float*)d_in[4];
  const float* b_o   = (const float*)d_in[5];
  const float* ln1w  = (const float*)d_in[6];
  const float* ln1b  = (const float*)d_in[7];
  const float* ln2w  = (const float*)d_in[8];
  const float* ln2b  = (const float*)d_in[9];
  const float* W1    = (const float*)d_in[10];
  const float* b1    = (const float*)d_in[11];
  const float* W2    = (const float*)d_in[12];
  const float* b2    = (const float*)d_in[13];
  const float* freqs = (const float*)d_in[14];
  float* out = (float*)d_out;

  char* ws = (char*)d_ws;
  const size_t MB = (size_t)1 << 20;
  bf16* h1   = (bf16*)(ws + 0 * MB);
  bf16* h2   = (bf16*)(ws + 8 * MB);
  bf16* wQKV = (bf16*)(ws + 16 * MB);
  bf16* wCat = (bf16*)(ws + 22 * MB);
  bf16* w1   = (bf16*)(ws + 32 * MB);
  bf16* qkv  = (bf16*)(ws + 40 * MB);
  bf16* Qb   = (bf16*)(ws + 64 * MB);
  bf16* Kb   = (bf16*)(ws + 72 * MB);
  bf16* VTb  = (bf16*)(ws + 80 * MB);
  bf16* A2   = (bf16*)(ws + 88 * MB);
  bf16* q0   = (bf16*)(ws + 0 * MB);
  bf16* q1   = (bf16*)(ws + 8 * MB);
  bf16* q2   = (bf16*)(ws + 40 * MB);
  bf16* q3   = (bf16*)(ws + 48 * MB);

  ln_cast_all<<<13312, 256, 0, stream>>>(x, ln1w, ln1b, ln2w, ln2b, h1, h2,
                                         W_qkv, W1, W_o, W2, wQKV, w1, wCat);
  gemm256<0><<<192, 512, 0, stream>>>(h1, wQKV, b_qkv, qkv,
                                      nullptr, nullptr, nullptr,
                                      1024, 3072, 192, 12, 16);
  rope_reshape<<<dim3(32, 32), 256, 0, stream>>>(qkv, freqs, Qb, Kb, VTb);
  attn_kernel<<<512, 512, 0, stream>>>(Qb, Kb, VTb, A2, 5120);
  gemm256<1><<<256, 512, 0, stream>>>(h2, w1, b1, A2 + 1024,
                                      nullptr, nullptr, nullptr,
                                      1024, 5120, 256, 16, 16);
  gemm256<2><<<256, 512, 0, stream>>>(A2, wCat, nullptr, q0,
                                      q1, q2, q3,
                                      5120, 1024, 64, 4, 20);
  combine_out<<<4096, 256, 0, stream>>>(q0, q1, q2, q3, x, b_o, b2, out);
}

// Round 15
// 186.426 us; speedup vs baseline: 1.0943x; 1.0483x over previous
//
#include <hip/hip_runtime.h>

#define DEV __device__ __forceinline__

typedef __bf16 bf16;
typedef bf16 bf16x4 __attribute__((ext_vector_type(4)));
typedef bf16 bf16x8 __attribute__((ext_vector_type(8)));
typedef float f32x4 __attribute__((ext_vector_type(4)));

DEV f32x4 mfma16(bf16x8 a, bf16x8 b, f32x4 c) {
  return __builtin_amdgcn_mfma_f32_16x16x32_bf16(a, b, c, 0, 0, 0);
}

DEV void gload_lds16(const bf16* g, bf16* l) {
  __builtin_amdgcn_global_load_lds((const __attribute__((address_space(1))) void*)g,
                                   (__attribute__((address_space(3))) void*)l, 16, 0, 0);
}

#define PH_BAR __builtin_amdgcn_s_barrier()
#define VM(NSTR) asm volatile("s_waitcnt vmcnt(" NSTR ")" ::: "memory")
#define WAITBAR(NSTR) asm volatile("s_waitcnt vmcnt(" NSTR ")\n\ts_barrier" ::: "memory")

// tanh-form GELU, exp2+rcp based (~8 VALU ops, overflow-safe both tails).
DEV float fast_gelu(float x) {
  const float z = x * x;
  const float w = __builtin_fmaf(z, 0.1029353f, 2.3019853f);
  const float e = __builtin_amdgcn_exp2f(x * w);
  const float r = __builtin_amdgcn_rcpf(1.0f + e);
  return x - x * r;
}

// ---------------- fused LayerNorm (rows) + all weight casts ----------------
__global__ __launch_bounds__(256) void ln_cast_all(
    const float* __restrict__ x,
    const float* __restrict__ ln1w, const float* __restrict__ ln1b,
    const float* __restrict__ ln2w, const float* __restrict__ ln2b,
    bf16* __restrict__ h1, bf16* __restrict__ h2,
    const float* __restrict__ Wqkv_f, const float* __restrict__ W1_f,
    const float* __restrict__ Wo_f, const float* __restrict__ W2_f,
    bf16* __restrict__ wQKV, bf16* __restrict__ w1, bf16* __restrict__ wCat)
{
  const int b = blockIdx.x, t = threadIdx.x;
  if (b < 4096) {
    __shared__ float red[2][4];
    const int lane = t & 63, wave = t >> 6;
    const float4 v = ((const float4*)(x + (size_t)b * 1024))[t];
    float vv[4] = {v.x, v.y, v.z, v.w};
    float s = vv[0] + vv[1] + vv[2] + vv[3];
    float q = vv[0]*vv[0] + vv[1]*vv[1] + vv[2]*vv[2] + vv[3]*vv[3];
    #pragma unroll
    for (int o = 32; o; o >>= 1) { s += __shfl_xor(s, o); q += __shfl_xor(q, o); }
    if (lane == 0) { red[0][wave] = s; red[1][wave] = q; }
    __syncthreads();
    s = red[0][0] + red[0][1] + red[0][2] + red[0][3];
    q = red[1][0] + red[1][1] + red[1][2] + red[1][3];
    const float mu = s * (1.0f / 1024.0f);
    const float var = q * (1.0f / 1024.0f) - mu * mu;
    const float rs = rsqrtf(var + 1e-5f);
    bf16x4 o1, o2;
    #pragma unroll
    for (int j = 0; j < 4; ++j) {
      const int i = t * 4 + j;
      const float xh = (vv[j] - mu) * rs;
      o1[j] = (bf16)(xh * ln1w[i] + ln1b[i]);
      o2[j] = (bf16)(xh * ln2w[i] + ln2b[i]);
    }
    *(bf16x4*)&h1[(size_t)b * 1024 + t * 4] = o1;
    *(bf16x4*)&h2[(size_t)b * 1024 + t * 4] = o2;
    return;
  }
  const int cb = b - 4096;
  if (cb < 3072) {
    const int i = cb * 256 + t;
    const float4 v = ((const float4*)Wqkv_f)[i];
    bf16x4 o = {(bf16)v.x, (bf16)v.y, (bf16)v.z, (bf16)v.w};
    ((bf16x4*)wQKV)[i] = o;
  } else if (cb < 7168) {
    const int i = (cb - 3072) * 256 + t;
    const float4 v = ((const float4*)W1_f)[i];
    bf16x4 o = {(bf16)v.x, (bf16)v.y, (bf16)v.z, (bf16)v.w};
    ((bf16x4*)w1)[i] = o;
  } else if (cb < 8192) {
    const int row = cb - 7168;
    const float4 v = *(const float4*)&Wo_f[(size_t)row * 1024 + t * 4];
    bf16x4 o = {(bf16)v.x, (bf16)v.y, (bf16)v.z, (bf16)v.w};
    *(bf16x4*)&wCat[(size_t)row * 5120 + t * 4] = o;
  } else {
    const int row = cb - 8192;
    #pragma unroll
    for (int k = 0; k < 4; ++k) {
      const int col = t * 4 + k * 1024;
      const float4 v = *(const float4*)&W2_f[(size_t)row * 4096 + col];
      bf16x4 o = {(bf16)v.x, (bf16)v.y, (bf16)v.z, (bf16)v.w};
      *(bf16x4*)&wCat[(size_t)row * 5120 + 1024 + col] = o;
    }
  }
}

// ---------------- GEMM 256x256xBK64 core (m201-style 4-phase) ----------------
DEV bf16x8 ldfrag(const bf16* unit, int lr, int g) {
  return *(const bf16x8*)&unit[lr * 32 + ((g ^ ((lr >> 1) & 3)) << 3)];
}
DEV void read_bfr(const bf16* unit, int blr, int g, bf16x8 bfr[4]) {
  #pragma unroll
  for (int nj = 0; nj < 4; ++nj) bfr[nj] = ldfrag(unit, blr + nj * 16, g);
}
DEV void read_af(const bf16* unit, int alr, int g, bf16x8 af[4]) {
  #pragma unroll
  for (int ml = 0; ml < 4; ++ml) af[ml] = ldfrag(unit, alr + ml * 16, g);
}
DEV void do_mfma(const bf16x8 af[4], const bf16x8 bfr[4], f32x4 acc[8][4], int mh) {
  __builtin_amdgcn_s_setprio(1);
  #pragma unroll
  for (int ml = 0; ml < 4; ++ml)
    #pragma unroll
    for (int nj = 0; nj < 4; ++nj)
      acc[mh * 4 + ml][nj] = mfma16(af[ml], bfr[nj], acc[mh * 4 + ml][nj]);
  __builtin_amdgcn_s_setprio(0);
}

// K-loop shared by all GEMM kernels. As/Bs: [2][2][2][4096].
DEV void gemm_kloop(bf16 (*As)[2][2][4096], bf16 (*Bs)[2][2][4096],
                    const bf16* aU[2][2], const bf16* bU[2][2],
                    int wave, int alr, int blr, int bub, int g, int nkt,
                    f32x4 acc[8][4])
{
  bf16x8 bfr[4], af[4];
#define STG_A(bf_, kkh_, ub_, ko_) gload_lds16(aU[kkh_][ub_] + (ko_), &As[bf_][kkh_][ub_][wave * 512])
#define STG_B(bf_, kkh_, ub_, ko_) gload_lds16(bU[kkh_][ub_] + (ko_), &Bs[bf_][kkh_][ub_][wave * 512])
  STG_B(0, 0, 0, 0); STG_B(0, 0, 1, 0); STG_A(0, 0, 0, 0); STG_A(0, 0, 1, 0);
  STG_B(0, 1, 0, 0); STG_B(0, 1, 1, 0); STG_A(0, 1, 0, 0); STG_A(0, 1, 1, 0);
  WAITBAR("4");

  for (int t = 0; t < nkt - 1; ++t) {
    const int buf = t & 1, nxt = buf ^ 1;
    const int ko = (t + 1) * 64;
    read_bfr(&Bs[buf][0][bub][0], blr, g, bfr);
    read_af(&As[buf][0][0][0], alr, g, af);
    STG_B(nxt, 0, 0, ko); STG_B(nxt, 0, 1, ko);
    PH_BAR;
    do_mfma(af, bfr, acc, 0);
    PH_BAR;
    read_af(&As[buf][0][1][0], alr, g, af);
    STG_A(nxt, 0, 0, ko); STG_A(nxt, 0, 1, ko);
    PH_BAR;
    do_mfma(af, bfr, acc, 1);
    VM("4");
    PH_BAR;
    read_bfr(&Bs[buf][1][bub][0], blr, g, bfr);
    read_af(&As[buf][1][0][0], alr, g, af);
    STG_B(nxt, 1, 0, ko); STG_B(nxt, 1, 1, ko);
    PH_BAR;
    do_mfma(af, bfr, acc, 0);
    PH_BAR;
    read_af(&As[buf][1][1][0], alr, g, af);
    STG_A(nxt, 1, 0, ko); STG_A(nxt, 1, 1, ko);
    PH_BAR;
    do_mfma(af, bfr, acc, 1);
    VM("4");
    PH_BAR;
  }
  {
    const int buf = (nkt - 1) & 1;
    read_bfr(&Bs[buf][0][bub][0], blr, g, bfr);
    read_af(&As[buf][0][0][0], alr, g, af);
    PH_BAR;
    do_mfma(af, bfr, acc, 0);
    PH_BAR;
    read_af(&As[buf][0][1][0], alr, g, af);
    PH_BAR;
    do_mfma(af, bfr, acc, 1);
    VM("0");
    PH_BAR;
    read_bfr(&Bs[buf][1][bub][0], blr, g, bfr);
    read_af(&As[buf][1][0][0], alr, g, af);
    PH_BAR;
    do_mfma(af, bfr, acc, 0);
    PH_BAR;
    read_af(&As[buf][1][1][0], alr, g, af);
    PH_BAR;
    do_mfma(af, bfr, acc, 1);
  }
#undef STG_A
#undef STG_B
}

// EPI: 0 = bf16 + bias; 1 = bf16 gelu(acc+bias); 2 = bf16 partial (split-K);
//      3 = QKV fused epilogue: bias + RoPE + head-split + Q-scale + V^T.
//          Cv=Qb [B*H][S][64], P1=Kb same, P2=VTb [B*H][64][S].
template <int EPI>
__global__ __launch_bounds__(512) void gemm256(
    const bf16* __restrict__ A, const bf16* __restrict__ B,
    const float* __restrict__ bias, void* __restrict__ Cv,
    void* __restrict__ P1, void* __restrict__ P2, void* __restrict__ P3,
    const float* __restrict__ freqs,
    int K, int ldc, int ntiles, int nbx, int nkt)
{
  __shared__ __align__(16) bf16 As[2][2][2][4096];
  __shared__ __align__(16) bf16 Bs[2][2][2][4096];
  const int tid = threadIdx.x;
  const int lane = tid & 63, wave = tid >> 6;
  const int wm = wave >> 2, wn = wave & 3;
  const int g = lane >> 4, c = lane & 15;
  const int cpx = gridDim.x >> 3;
  const int swz = ((int)blockIdx.x & 7) * cpx + ((int)blockIdx.x >> 3);
  const int tile = swz % ntiles;
  const int sk = swz / ntiles;
  const int bm = (tile / nbx) * 256, bn = (tile % nbx) * 256;

  const int slr = tid >> 2;
  const int sch = (tid & 3) ^ ((tid >> 3) & 3);
  const bf16* aU[2][2];
  const bf16* bU[2][2];
  {
    const bf16* a0 = A + (size_t)(bm + ((slr >> 6) * 128) + (slr & 63)) * K
                       + (size_t)sk * nkt * 64 + sch * 8;
    const bf16* b0 = B + (size_t)(bn + slr) * K + (size_t)sk * nkt * 64 + sch * 8;
    aU[0][0] = a0;            aU[0][1] = a0 + (size_t)64 * K;
    aU[1][0] = a0 + 32;       aU[1][1] = a0 + (size_t)64 * K + 32;
    bU[0][0] = b0;            bU[0][1] = b0 + (size_t)128 * K;
    bU[1][0] = b0 + 32;       bU[1][1] = b0 + (size_t)128 * K + 32;
  }

  f32x4 acc[8][4] = {};
  const int alr = (wm << 6) + c;
  const int blr = ((wn & 1) << 6) + c;
  const int bub = wn >> 1;

  gemm_kloop(As, Bs, aU, bU, wave, alr, blr, bub, g, nkt, acc);

  const int row0 = bm + wm * 128 + 4 * g;
  const int col0 = bn + wn * 64 + c;

  if constexpr (EPI == 3) {
    bf16* Qb  = (bf16*)Cv;
    bf16* Kb  = (bf16*)P1;
    bf16* VTb = (bf16*)P2;
    const int which = bn >> 10;                    // block-uniform
    const int h = ((bn & 1023) >> 6) + wn;         // wave-uniform
    #pragma unroll
    for (int mi = 0; mi < 8; ++mi) {
      const int srow = row0 + mi * 16;
      const int bb = srow >> 11, sl0 = srow & 2047;
      #pragma unroll
      for (int nj = 0; nj < 4; ++nj) {
        const int d = nj * 16 + c;
        const float bv = bias[bn + wn * 64 + d];
        float vo[4];
        #pragma unroll
        for (int r = 0; r < 4; ++r) vo[r] = acc[mi][nj][r] + bv;
        if (which == 2) {
          bf16x4 o = {(bf16)vo[0], (bf16)vo[1], (bf16)vo[2], (bf16)vo[3]};
          *(bf16x4*)&VTb[((size_t)(bb * 16 + h) * 64 + d) * 2048 + sl0] = o;
        } else {
          if (nj == 0) {  // RoPE on d<16: pair lanes c <-> c^8
            #pragma unroll
            for (int r = 0; r < 4; ++r) {
              const int sl = sl0 + r;
              const float cs = freqs[sl * 16 + (c & 7) * 2];
              const float sn = freqs[sl * 16 + (c & 7) * 2 + 1];
              const float p = __shfl_xor(vo[r], 8);
              vo[r] = (c < 8) ? (vo[r] * cs - p * sn) : (p * sn + vo[r] * cs);
            }
          }
          bf16* dst = (which == 0) ? Qb : Kb;
          const float sc = (which == 0) ? 0.18033688f /*0.125*log2(e)*/ : 1.0f;
          #pragma unroll
          for (int r = 0; r < 4; ++r)
            dst[((size_t)(bb * 16 + h) * 2048 + (sl0 + r)) * 64 + d] = (bf16)(vo[r] * sc);
        }
      }
    }
    return;
  }

  bf16* Pp = nullptr;
  if constexpr (EPI == 2)
    Pp = (bf16*)((sk == 1) ? P1 : (sk == 2) ? P2 : (sk == 3) ? P3 : Cv);
  #pragma unroll
  for (int mi = 0; mi < 8; ++mi) {
    #pragma unroll
    for (int nj = 0; nj < 4; ++nj) {
      const int col = col0 + nj * 16;
      float bv = 0.0f;
      if constexpr (EPI < 2) bv = bias[col];
      #pragma unroll
      for (int r = 0; r < 4; ++r) {
        const size_t idx = (size_t)(row0 + mi * 16 + r) * ldc + col;
        float vo = acc[mi][nj][r] + bv;
        if constexpr (EPI == 0) {
          ((bf16*)Cv)[idx] = (bf16)vo;
        } else if constexpr (EPI == 1) {
          ((bf16*)Cv)[idx] = (bf16)fast_gelu(vo);
        } else {
          Pp[idx] = (bf16)vo;
        }
      }
    }
  }
}

// ---------------- combine: out = q0+q1+q2+q3 + x + b_o + b2 ----------------
__global__ __launch_bounds__(256) void combine_out(
    const bf16* __restrict__ q0, const bf16* __restrict__ q1,
    const bf16* __restrict__ q2, const bf16* __restrict__ q3,
    const float* __restrict__ x,
    const float* __restrict__ bo, const float* __restrict__ b2,
    float* __restrict__ out)
{
  const int row = blockIdx.x, t = threadIdx.x;
  const size_t base = (size_t)row * 1024 + t * 4;
  const bf16x4 a0 = *(const bf16x4*)&q0[base];
  const bf16x4 a1 = *(const bf16x4*)&q1[base];
  const bf16x4 a2 = *(const bf16x4*)&q2[base];
  const bf16x4 a3 = *(const bf16x4*)&q3[base];
  const float4 vx = *(const float4*)&x[base];
  const float4 vb = *(const float4*)&bo[t * 4];
  const float4 vc = *(const float4*)&b2[t * 4];
  float4 o;
  o.x = (float)a0[0] + (float)a1[0] + (float)a2[0] + (float)a3[0] + vx.x + vb.x + vc.x;
  o.y = (float)a0[1] + (float)a1[1] + (float)a2[1] + (float)a3[1] + vx.y + vb.y + vc.y;
  o.z = (float)a0[2] + (float)a1[2] + (float)a2[2] + (float)a3[2] + vx.z + vb.z + vc.z;
  o.w = (float)a0[3] + (float)a1[3] + (float)a2[3] + (float)a3[3] + vx.w + vb.w + vc.w;
  *(float4*)&out[base] = o;
}

// ---------------- Causal flash attention (v6c) ----------------
// v6 structure (QBLK=128, 512 thr, 4-buffer K/V, counted vmcnt(2),
// qkt-ahead pipeline, heavy/light pairing). R15: 4-body-unrolled quad loop
// makes LDS buffer indices compile-time -> ds_read immediate offsets (no
// per-read VALU address adds). Q arrives pre-scaled (QKV epilogue folds
// 0.125*log2e), so qreg loads raw.
__global__ __launch_bounds__(512, 4) void attn_kernel(
    const bf16* __restrict__ Q, const bf16* __restrict__ Kg,
    const bf16* __restrict__ VTg, bf16* __restrict__ O, int ldO)
{
  __shared__ __align__(16) bf16 Ks[4][64][64];
  __shared__ __align__(16) bf16 Vs[4][64][64];
  __shared__ __align__(16) bf16 Ps[8][16][64];

  const int tid = threadIdx.x;
  const int lane = tid & 63, wave = tid >> 6;
  const int g = lane >> 4, c = lane & 15;
  const int L = blockIdx.x;
  const int heavy = (L < 256);
  const int r = heavy ? L : (L - 256);
  const int bh = r >> 3;
  const int qtile = heavy ? (8 + (r & 7)) : (7 - (r & 7));
  const int qw = qtile * 128 + wave * 16;

  const bf16* Qp = Q + (size_t)bh * 2048 * 64;
  const bf16* Kp = Kg + (size_t)bh * 2048 * 64;
  const bf16* Vp = VTg + (size_t)bh * 64 * 2048;

  const int srow = lane >> 3;
  const int schunk = (lane & 7) ^ srow;
  const int svr = wave * 8 + srow;

  bf16x8 qreg[2];
  qreg[0] = *(const bf16x8*)&Qp[(size_t)(qw + c) * 64 + g * 8];
  qreg[1] = *(const bf16x8*)&Qp[(size_t)(qw + c) * 64 + 32 + g * 8];
  bf16x8 ones;
  #pragma unroll
  for (int j = 0; j < 8; ++j) ones[j] = (bf16)1.0f;

  const int cq = c & 7;
  int fo[4][2];
  #pragma unroll
  for (int i = 0; i < 4; ++i)
    #pragma unroll
    for (int kk = 0; kk < 2; ++kk)
      fo[i][kk] = (i * 16 + c) * 64 + (((kk * 4 + g) ^ cq) << 3);
  bf16* pw[4];
  #pragma unroll
  for (int kf = 0; kf < 4; ++kf)
    pw[kf] = &Ps[wave][c][((((kf * 2 + (g >> 1)) ^ cq) << 3)) + ((g & 1) << 2)];
  const bf16* pr[2];
  #pragma unroll
  for (int kk = 0; kk < 2; ++kk)
    pr[kk] = &Ps[wave][c][((kk * 4 + g) ^ cq) << 3];

  bf16* const kdst[4] = {&Ks[0][0][0] + wave * 512, &Ks[1][0][0] + wave * 512,
                         &Ks[2][0][0] + wave * 512, &Ks[3][0][0] + wave * 512};
  bf16* const vdst[4] = {&Vs[0][0][0] + wave * 512, &Vs[1][0][0] + wave * 512,
                         &Vs[2][0][0] + wave * 512, &Vs[3][0][0] + wave * 512};

  f32x4 oacc[4] = {};
  f32x4 lacc = {};
  float m_ = -1e30f;

  const int nkb = 2 * qtile + 2;  // even, >= 2
#define STAGE(j_, B4_) do {                                                         \
    gload_lds16(&Kp[(size_t)((j_) * 64 + svr) * 64 + schunk * 8], kdst[B4_]);       \
    gload_lds16(&Vp[(size_t)svr * 2048 + (j_) * 64 + schunk * 8], vdst[B4_]);       \
  } while (0)

  auto qkt = [&](f32x4* st, const bf16* kt) {
    __builtin_amdgcn_s_setprio(1);
    #pragma unroll
    for (int kf = 0; kf < 4; ++kf) {
      f32x4 z = {};
      z = mfma16(*(const bf16x8*)(kt + fo[kf][0]), qreg[0], z);
      st[kf] = mfma16(*(const bf16x8*)(kt + fo[kf][1]), qreg[1], z);
    }
    __builtin_amdgcn_s_setprio(0);
  };

  auto smpv = [&](const f32x4* st, int j_, const bf16* vt) {
    const int kbase = j_ * 64;
    float v[16];
    if (kbase + 63 > qw) {
      const int qrel = qw + c - kbase;
      #pragma unroll
      for (int kf = 0; kf < 4; ++kf)
        #pragma unroll
        for (int rr = 0; rr < 4; ++rr)
          v[kf * 4 + rr] = (kf * 16 + 4 * g + rr <= qrel) ? st[kf][rr] : -1e30f;
    } else {
      #pragma unroll
      for (int kf = 0; kf < 4; ++kf)
        #pragma unroll
        for (int rr = 0; rr < 4; ++rr)
          v[kf * 4 + rr] = st[kf][rr];
    }
    float u0 = fmaxf(fmaxf(v[0], v[1]), v[2]);
    float u1 = fmaxf(fmaxf(v[3], v[4]), v[5]);
    float u2 = fmaxf(fmaxf(v[6], v[7]), v[8]);
    float u3 = fmaxf(fmaxf(v[9], v[10]), v[11]);
    float u4 = fmaxf(fmaxf(v[12], v[13]), v[14]);
    float tm = fmaxf(fmaxf(fmaxf(u0, u1), u2), fmaxf(fmaxf(u3, u4), v[15]));
    if (__any(tm > m_ + 8.0f)) {
      float tr = fmaxf(tm, __shfl_xor(tm, 16));
      tr = fmaxf(tr, __shfl_xor(tr, 32));
      const float mn = fmaxf(m_, tr);
      const float alpha = __builtin_amdgcn_exp2f(m_ - mn);
      m_ = mn;
      lacc[0] *= alpha; lacc[1] *= alpha; lacc[2] *= alpha; lacc[3] *= alpha;
      #pragma unroll
      for (int df = 0; df < 4; ++df) {
        oacc[df][0] *= alpha; oacc[df][1] *= alpha;
        oacc[df][2] *= alpha; oacc[df][3] *= alpha;
      }
    }
    bf16 pq[16];
    #pragma unroll
    for (int i = 0; i < 16; ++i)
      pq[i] = (bf16)__builtin_amdgcn_exp2f(v[i] - m_);
    #pragma unroll
    for (int kf = 0; kf < 4; ++kf) {
      bf16x4 pk = {pq[kf * 4], pq[kf * 4 + 1], pq[kf * 4 + 2], pq[kf * 4 + 3]};
      *(bf16x4*)pw[kf] = pk;
    }
    bf16x8 pfrag0 = *(const bf16x8*)pr[0];
    bf16x8 pfrag1 = *(const bf16x8*)pr[1];
    __builtin_amdgcn_s_setprio(1);
    #pragma unroll
    for (int df = 0; df < 4; ++df) {
      oacc[df] = mfma16(*(const bf16x8*)(vt + fo[df][0]), pfrag0, oacc[df]);
      oacc[df] = mfma16(*(const bf16x8*)(vt + fo[df][1]), pfrag1, oacc[df]);
    }
    lacc = mfma16(ones, pfrag0, lacc);
    lacc = mfma16(ones, pfrag1, lacc);
    __builtin_amdgcn_s_setprio(0);
  };

  // body j with compile-time buffer index BUF = j&3 (static LDS addressing)
#define ABODY(j_, BUF, stC, stN) do {                                          \
    const bool stg_ = ((j_) + 3 < nkb);                                        \
    if (stg_) STAGE((j_) + 3, (((BUF) + 3) & 3));                              \
    if (((j_) + 1) < nkb && ((j_) + 1) * 64 <= qw + 15)                        \
      qkt(stN, &Ks[((BUF) + 1) & 3][0][0]);                                    \
    if ((j_) * 64 <= qw + 15) smpv(stC, (j_), &Vs[(BUF)][0][0]);               \
    if (stg_) { VM("2"); } else { VM("0"); }                                   \
    PH_BAR;                                                                    \
  } while (0)

  f32x4 stA[4], stB[4];
  STAGE(0, 0); STAGE(1, 1); STAGE(2, 2);
  VM("2");   // S0,S1 drained; S2 in flight
  PH_BAR;
  qkt(stA, &Ks[0][0][0]);

  const int nq = nkb >> 2;
  for (int qd = 0; qd < nq; ++qd) {
    const int j0 = 4 * qd;
    ABODY(j0 + 0, 0, stA, stB);
    ABODY(j0 + 1, 1, stB, stA);
    ABODY(j0 + 2, 2, stA, stB);
    ABODY(j0 + 3, 3, stB, stA);
  }
  if (nkb & 2) {
    ABODY(nkb - 2, 0, stA, stB);
    ABODY(nkb - 1, 1, stB, stA);
  }
#undef ABODY
#undef STAGE

  const int b = bh >> 4, h = bh & 15;
  const float inv = 1.0f / lacc[0];
  const int s = qw + c;
  #pragma unroll
  for (int df = 0; df < 4; ++df) {
    bf16x4 o;
    #pragma unroll
    for (int rr = 0; rr < 4; ++rr) o[rr] = (bf16)(oacc[df][rr] * inv);
    *(bf16x4*)&O[(size_t)(b * 2048 + s) * ldO + h * 64 + df * 16 + 4 * g] = o;
  }
}

// ---------------- host orchestration ----------------
extern "C" void kernel_launch(void* const* d_in, const int* in_sizes, int n_in,
                              void* d_out, int out_size, void* d_ws, size_t ws_size,
                              hipStream_t stream) {
  const float* x     = (const float*)d_in[0];
  const float* W_qkv = (const float*)d_in[2];
  const float* b_qkv = (const float*)d_in[3];
  const float* W_o   = (const float*)d_in[4];
  const float* b_o   = (const float*)d_in[5];
  const float* ln1w  = (const float*)d_in[6];
  const float* ln1b  = (const float*)d_in[7];
  const float* ln2w  = (const float*)d_in[8];
  const float* ln2b  = (const float*)d_in[9];
  const float* W1    = (const float*)d_in[10];
  const float* b1    = (const float*)d_in[11];
  const float* W2    = (const float*)d_in[12];
  const float* b2    = (const float*)d_in[13];
  const float* freqs = (const float*)d_in[14];
  float* out = (float*)d_out;

  char* ws = (char*)d_ws;
  const size_t MB = (size_t)1 << 20;
  bf16* h1   = (bf16*)(ws + 0 * MB);
  bf16* h2   = (bf16*)(ws + 8 * MB);
  bf16* wQKV = (bf16*)(ws + 16 * MB);
  bf16* wCat = (bf16*)(ws + 22 * MB);
  bf16* w1   = (bf16*)(ws + 32 * MB);
  bf16* Qb   = (bf16*)(ws + 64 * MB);
  bf16* Kb   = (bf16*)(ws + 72 * MB);
  bf16* VTb  = (bf16*)(ws + 80 * MB);
  bf16* A2   = (bf16*)(ws + 88 * MB);
  bf16* q0   = (bf16*)(ws + 0 * MB);
  bf16* q1   = (bf16*)(ws + 8 * MB);
  bf16* q2   = (bf16*)(ws + 40 * MB);
  bf16* q3   = (bf16*)(ws + 48 * MB);

  ln_cast_all<<<13312, 256, 0, stream>>>(x, ln1w, ln1b, ln2w, ln2b, h1, h2,
                                         W_qkv, W1, W_o, W2, wQKV, w1, wCat);
  // QKV with fused RoPE/head-split/Q-scale/V^T epilogue
  gemm256<3><<<192, 512, 0, stream>>>(h1, wQKV, b_qkv, Qb,
                                      Kb, VTb, nullptr, freqs,
                                      1024, 3072, 192, 12, 16);
  attn_kernel<<<512, 512, 0, stream>>>(Qb, Kb, VTb, A2, 5120);
  gemm256<1><<<256, 512, 0, stream>>>(h2, w1, b1, A2 + 1024,
                                      nullptr, nullptr, nullptr, nullptr,
                                      1024, 5120, 256, 16, 16);
  gemm256<2><<<256, 512, 0, stream>>>(A2, wCat, nullptr, q0,
                                      q1, q2, q3, nullptr,
                                      5120, 1024, 64, 4, 20);
  combine_out<<<4096, 256, 0, stream>>>(q0, q1, q2, q3, x, b_o, b2, out);
}

// Round 16
// 184.335 us; speedup vs baseline: 1.1067x; 1.0113x over previous
//
#include <hip/hip_runtime.h>

#define DEV __device__ __forceinline__

typedef __bf16 bf16;
typedef bf16 bf16x4 __attribute__((ext_vector_type(4)));
typedef bf16 bf16x8 __attribute__((ext_vector_type(8)));
typedef float f32x4 __attribute__((ext_vector_type(4)));

DEV f32x4 mfma16(bf16x8 a, bf16x8 b, f32x4 c) {
  return __builtin_amdgcn_mfma_f32_16x16x32_bf16(a, b, c, 0, 0, 0);
}

DEV void gload_lds16(const bf16* g, bf16* l) {
  __builtin_amdgcn_global_load_lds((const __attribute__((address_space(1))) void*)g,
                                   (__attribute__((address_space(3))) void*)l, 16, 0, 0);
}

#define PH_BAR __builtin_amdgcn_s_barrier()
#define VM(NSTR) asm volatile("s_waitcnt vmcnt(" NSTR ")" ::: "memory")
// counted vmcnt + full LDS-read drain before a barrier that releases overwrites
#define VMLG(NSTR) asm volatile("s_waitcnt vmcnt(" NSTR ") lgkmcnt(0)" ::: "memory")
#define WAITBAR(NSTR) asm volatile("s_waitcnt vmcnt(" NSTR ")\n\ts_barrier" ::: "memory")

// tanh-form GELU, exp2+rcp based (~8 VALU ops, overflow-safe both tails).
DEV float fast_gelu(float x) {
  const float z = x * x;
  const float w = __builtin_fmaf(z, 0.1029353f, 2.3019853f);
  const float e = __builtin_amdgcn_exp2f(x * w);
  const float r = __builtin_amdgcn_rcpf(1.0f + e);
  return x - x * r;
}

// ---------------- fused LayerNorm (rows) + all weight casts ----------------
__global__ __launch_bounds__(256) void ln_cast_all(
    const float* __restrict__ x,
    const float* __restrict__ ln1w, const float* __restrict__ ln1b,
    const float* __restrict__ ln2w, const float* __restrict__ ln2b,
    bf16* __restrict__ h1, bf16* __restrict__ h2,
    const float* __restrict__ Wqkv_f, const float* __restrict__ W1_f,
    const float* __restrict__ Wo_f, const float* __restrict__ W2_f,
    bf16* __restrict__ wQKV, bf16* __restrict__ w1, bf16* __restrict__ wCat)
{
  const int b = blockIdx.x, t = threadIdx.x;
  if (b < 4096) {
    __shared__ float red[2][4];
    const int lane = t & 63, wave = t >> 6;
    const float4 v = ((const float4*)(x + (size_t)b * 1024))[t];
    float vv[4] = {v.x, v.y, v.z, v.w};
    float s = vv[0] + vv[1] + vv[2] + vv[3];
    float q = vv[0]*vv[0] + vv[1]*vv[1] + vv[2]*vv[2] + vv[3]*vv[3];
    #pragma unroll
    for (int o = 32; o; o >>= 1) { s += __shfl_xor(s, o); q += __shfl_xor(q, o); }
    if (lane == 0) { red[0][wave] = s; red[1][wave] = q; }
    __syncthreads();
    s = red[0][0] + red[0][1] + red[0][2] + red[0][3];
    q = red[1][0] + red[1][1] + red[1][2] + red[1][3];
    const float mu = s * (1.0f / 1024.0f);
    const float var = q * (1.0f / 1024.0f) - mu * mu;
    const float rs = rsqrtf(var + 1e-5f);
    bf16x4 o1, o2;
    #pragma unroll
    for (int j = 0; j < 4; ++j) {
      const int i = t * 4 + j;
      const float xh = (vv[j] - mu) * rs;
      o1[j] = (bf16)(xh * ln1w[i] + ln1b[i]);
      o2[j] = (bf16)(xh * ln2w[i] + ln2b[i]);
    }
    *(bf16x4*)&h1[(size_t)b * 1024 + t * 4] = o1;
    *(bf16x4*)&h2[(size_t)b * 1024 + t * 4] = o2;
    return;
  }
  const int cb = b - 4096;
  if (cb < 3072) {
    const int i = cb * 256 + t;
    const float4 v = ((const float4*)Wqkv_f)[i];
    bf16x4 o = {(bf16)v.x, (bf16)v.y, (bf16)v.z, (bf16)v.w};
    ((bf16x4*)wQKV)[i] = o;
  } else if (cb < 7168) {
    const int i = (cb - 3072) * 256 + t;
    const float4 v = ((const float4*)W1_f)[i];
    bf16x4 o = {(bf16)v.x, (bf16)v.y, (bf16)v.z, (bf16)v.w};
    ((bf16x4*)w1)[i] = o;
  } else if (cb < 8192) {
    const int row = cb - 7168;
    const float4 v = *(const float4*)&Wo_f[(size_t)row * 1024 + t * 4];
    bf16x4 o = {(bf16)v.x, (bf16)v.y, (bf16)v.z, (bf16)v.w};
    *(bf16x4*)&wCat[(size_t)row * 5120 + t * 4] = o;
  } else {
    const int row = cb - 8192;
    #pragma unroll
    for (int k = 0; k < 4; ++k) {
      const int col = t * 4 + k * 1024;
      const float4 v = *(const float4*)&W2_f[(size_t)row * 4096 + col];
      bf16x4 o = {(bf16)v.x, (bf16)v.y, (bf16)v.z, (bf16)v.w};
      *(bf16x4*)&wCat[(size_t)row * 5120 + 1024 + col] = o;
    }
  }
}

// ---------------- GEMM 256x256xBK64 core, 2-barrier/K-tile schedule ----------------
// R16: within a K-tile, ds_reads target buf and gload_lds target buf^1 — no
// cross-wave hazard. Barriers only at half-tile boundaries, each preceded by
// s_waitcnt vmcnt(4) lgkmcnt(0):
//   vmcnt(4): outstanding is always 8 at the wait; oldest 4 = the half about to
//   be read by all waves next (ledger: issue order per tile is
//   B00 B01 A00 A01 | B10 B11 A10 A11, so at the mid-tile wait the oldest 4 are
//   this tile's kk=1 units; at tile end they are next tile's kk=0 units).
//   lgkmcnt(0): this wave's LDS reads complete before it passes the barrier
//   that releases the stores overwriting the region (read-vs-overwrite hazard).
DEV bf16x8 ldfrag(const bf16* unit, int lr, int g) {
  return *(const bf16x8*)&unit[lr * 32 + ((g ^ ((lr >> 1) & 3)) << 3)];
}
DEV void read_bfr(const bf16* unit, int blr, int g, bf16x8 bfr[4]) {
  #pragma unroll
  for (int nj = 0; nj < 4; ++nj) bfr[nj] = ldfrag(unit, blr + nj * 16, g);
}
DEV void read_af(const bf16* unit, int alr, int g, bf16x8 af[4]) {
  #pragma unroll
  for (int ml = 0; ml < 4; ++ml) af[ml] = ldfrag(unit, alr + ml * 16, g);
}
DEV void do_mfma(const bf16x8 af[4], const bf16x8 bfr[4], f32x4 acc[8][4], int mh) {
  __builtin_amdgcn_s_setprio(1);
  #pragma unroll
  for (int ml = 0; ml < 4; ++ml)
    #pragma unroll
    for (int nj = 0; nj < 4; ++nj)
      acc[mh * 4 + ml][nj] = mfma16(af[ml], bfr[nj], acc[mh * 4 + ml][nj]);
  __builtin_amdgcn_s_setprio(0);
}

DEV void gemm_kloop(bf16 (*As)[2][2][4096], bf16 (*Bs)[2][2][4096],
                    const bf16* aU[2][2], const bf16* bU[2][2],
                    int wave, int alr, int blr, int bub, int g, int nkt,
                    f32x4 acc[8][4])
{
  bf16x8 bfr[4], af[4];
#define STG_A(bf_, kkh_, ub_, ko_) gload_lds16(aU[kkh_][ub_] + (ko_), &As[bf_][kkh_][ub_][wave * 512])
#define STG_B(bf_, kkh_, ub_, ko_) gload_lds16(bU[kkh_][ub_] + (ko_), &Bs[bf_][kkh_][ub_][wave * 512])
  STG_B(0, 0, 0, 0); STG_B(0, 0, 1, 0); STG_A(0, 0, 0, 0); STG_A(0, 0, 1, 0);
  STG_B(0, 1, 0, 0); STG_B(0, 1, 1, 0); STG_A(0, 1, 0, 0); STG_A(0, 1, 1, 0);
  WAITBAR("4");  // kk=0 of tile 0 landed; kk=1 (4 loads) in flight

  for (int t = 0; t < nkt - 1; ++t) {
    const int buf = t & 1, nxt = buf ^ 1;
    const int ko = (t + 1) * 64;
    // ---- half 0 (kk=0): no barriers inside — stages hit buf^1, reads hit buf
    read_bfr(&Bs[buf][0][bub][0], blr, g, bfr);
    read_af(&As[buf][0][0][0], alr, g, af);
    STG_B(nxt, 0, 0, ko); STG_B(nxt, 0, 1, ko);
    do_mfma(af, bfr, acc, 0);
    read_af(&As[buf][0][1][0], alr, g, af);
    STG_A(nxt, 0, 0, ko); STG_A(nxt, 0, 1, ko);
    do_mfma(af, bfr, acc, 1);
    VMLG("4");   // this tile's kk=1 landed; own reads drained
    PH_BAR;
    // ---- half 1 (kk=1)
    read_bfr(&Bs[buf][1][bub][0], blr, g, bfr);
    read_af(&As[buf][1][0][0], alr, g, af);
    STG_B(nxt, 1, 0, ko); STG_B(nxt, 1, 1, ko);
    do_mfma(af, bfr, acc, 0);
    read_af(&As[buf][1][1][0], alr, g, af);
    STG_A(nxt, 1, 0, ko); STG_A(nxt, 1, 1, ko);
    do_mfma(af, bfr, acc, 1);
    VMLG("4");   // next tile's kk=0 landed; own reads drained
    PH_BAR;
  }
  {  // final K-tile: no staging; entry invariant: kk=0 landed, kk=1 in flight
    const int buf = (nkt - 1) & 1;
    read_bfr(&Bs[buf][0][bub][0], blr, g, bfr);
    read_af(&As[buf][0][0][0], alr, g, af);
    do_mfma(af, bfr, acc, 0);
    read_af(&As[buf][0][1][0], alr, g, af);
    do_mfma(af, bfr, acc, 1);
    VMLG("0");
    PH_BAR;
    read_bfr(&Bs[buf][1][bub][0], blr, g, bfr);
    read_af(&As[buf][1][0][0], alr, g, af);
    do_mfma(af, bfr, acc, 0);
    read_af(&As[buf][1][1][0], alr, g, af);
    do_mfma(af, bfr, acc, 1);
  }
#undef STG_A
#undef STG_B
}

// EPI: 0 = bf16 + bias; 1 = bf16 gelu(acc+bias); 2 = bf16 partial (split-K);
//      3 = QKV fused epilogue: bias + RoPE + head-split + Q-scale + V^T.
template <int EPI>
__global__ __launch_bounds__(512) void gemm256(
    const bf16* __restrict__ A, const bf16* __restrict__ B,
    const float* __restrict__ bias, void* __restrict__ Cv,
    void* __restrict__ P1, void* __restrict__ P2, void* __restrict__ P3,
    const float* __restrict__ freqs,
    int K, int ldc, int ntiles, int nbx, int nkt)
{
  __shared__ __align__(16) bf16 As[2][2][2][4096];
  __shared__ __align__(16) bf16 Bs[2][2][2][4096];
  const int tid = threadIdx.x;
  const int lane = tid & 63, wave = tid >> 6;
  const int wm = wave >> 2, wn = wave & 3;
  const int g = lane >> 4, c = lane & 15;
  const int cpx = gridDim.x >> 3;
  const int swz = ((int)blockIdx.x & 7) * cpx + ((int)blockIdx.x >> 3);
  const int tile = swz % ntiles;
  const int sk = swz / ntiles;
  const int bm = (tile / nbx) * 256, bn = (tile % nbx) * 256;

  const int slr = tid >> 2;
  const int sch = (tid & 3) ^ ((tid >> 3) & 3);
  const bf16* aU[2][2];
  const bf16* bU[2][2];
  {
    const bf16* a0 = A + (size_t)(bm + ((slr >> 6) * 128) + (slr & 63)) * K
                       + (size_t)sk * nkt * 64 + sch * 8;
    const bf16* b0 = B + (size_t)(bn + slr) * K + (size_t)sk * nkt * 64 + sch * 8;
    aU[0][0] = a0;            aU[0][1] = a0 + (size_t)64 * K;
    aU[1][0] = a0 + 32;       aU[1][1] = a0 + (size_t)64 * K + 32;
    bU[0][0] = b0;            bU[0][1] = b0 + (size_t)128 * K;
    bU[1][0] = b0 + 32;       bU[1][1] = b0 + (size_t)128 * K + 32;
  }

  f32x4 acc[8][4] = {};
  const int alr = (wm << 6) + c;
  const int blr = ((wn & 1) << 6) + c;
  const int bub = wn >> 1;

  gemm_kloop(As, Bs, aU, bU, wave, alr, blr, bub, g, nkt, acc);

  const int row0 = bm + wm * 128 + 4 * g;
  const int col0 = bn + wn * 64 + c;

  if constexpr (EPI == 3) {
    bf16* Qb  = (bf16*)Cv;
    bf16* Kb  = (bf16*)P1;
    bf16* VTb = (bf16*)P2;
    const int which = bn >> 10;                    // block-uniform
    const int h = ((bn & 1023) >> 6) + wn;         // wave-uniform
    #pragma unroll
    for (int mi = 0; mi < 8; ++mi) {
      const int srow = row0 + mi * 16;
      const int bb = srow >> 11, sl0 = srow & 2047;
      #pragma unroll
      for (int nj = 0; nj < 4; ++nj) {
        const int d = nj * 16 + c;
        const float bv = bias[bn + wn * 64 + d];
        float vo[4];
        #pragma unroll
        for (int r = 0; r < 4; ++r) vo[r] = acc[mi][nj][r] + bv;
        if (which == 2) {
          bf16x4 o = {(bf16)vo[0], (bf16)vo[1], (bf16)vo[2], (bf16)vo[3]};
          *(bf16x4*)&VTb[((size_t)(bb * 16 + h) * 64 + d) * 2048 + sl0] = o;
        } else {
          if (nj == 0) {  // RoPE on d<16: pair lanes c <-> c^8
            #pragma unroll
            for (int r = 0; r < 4; ++r) {
              const int sl = sl0 + r;
              const float cs = freqs[sl * 16 + (c & 7) * 2];
              const float sn = freqs[sl * 16 + (c & 7) * 2 + 1];
              const float p = __shfl_xor(vo[r], 8);
              vo[r] = (c < 8) ? (vo[r] * cs - p * sn) : (p * sn + vo[r] * cs);
            }
          }
          bf16* dst = (which == 0) ? Qb : Kb;
          const float sc = (which == 0) ? 0.18033688f /*0.125*log2(e)*/ : 1.0f;
          #pragma unroll
          for (int r = 0; r < 4; ++r)
            dst[((size_t)(bb * 16 + h) * 2048 + (sl0 + r)) * 64 + d] = (bf16)(vo[r] * sc);
        }
      }
    }
    return;
  }

  bf16* Pp = nullptr;
  if constexpr (EPI == 2)
    Pp = (bf16*)((sk == 1) ? P1 : (sk == 2) ? P2 : (sk == 3) ? P3 : Cv);
  #pragma unroll
  for (int mi = 0; mi < 8; ++mi) {
    #pragma unroll
    for (int nj = 0; nj < 4; ++nj) {
      const int col = col0 + nj * 16;
      float bv = 0.0f;
      if constexpr (EPI < 2) bv = bias[col];
      #pragma unroll
      for (int r = 0; r < 4; ++r) {
        const size_t idx = (size_t)(row0 + mi * 16 + r) * ldc + col;
        float vo = acc[mi][nj][r] + bv;
        if constexpr (EPI == 0) {
          ((bf16*)Cv)[idx] = (bf16)vo;
        } else if constexpr (EPI == 1) {
          ((bf16*)Cv)[idx] = (bf16)fast_gelu(vo);
        } else {
          Pp[idx] = (bf16)vo;
        }
      }
    }
  }
}

// ---------------- combine: out = q0+q1+q2+q3 + x + b_o + b2 ----------------
__global__ __launch_bounds__(256) void combine_out(
    const bf16* __restrict__ q0, const bf16* __restrict__ q1,
    const bf16* __restrict__ q2, const bf16* __restrict__ q3,
    const float* __restrict__ x,
    const float* __restrict__ bo, const float* __restrict__ b2,
    float* __restrict__ out)
{
  const int row = blockIdx.x, t = threadIdx.x;
  const size_t base = (size_t)row * 1024 + t * 4;
  const bf16x4 a0 = *(const bf16x4*)&q0[base];
  const bf16x4 a1 = *(const bf16x4*)&q1[base];
  const bf16x4 a2 = *(const bf16x4*)&q2[base];
  const bf16x4 a3 = *(const bf16x4*)&q3[base];
  const float4 vx = *(const float4*)&x[base];
  const float4 vb = *(const float4*)&bo[t * 4];
  const float4 vc = *(const float4*)&b2[t * 4];
  float4 o;
  o.x = (float)a0[0] + (float)a1[0] + (float)a2[0] + (float)a3[0] + vx.x + vb.x + vc.x;
  o.y = (float)a0[1] + (float)a1[1] + (float)a2[1] + (float)a3[1] + vx.y + vb.y + vc.y;
  o.z = (float)a0[2] + (float)a1[2] + (float)a2[2] + (float)a3[2] + vx.z + vb.z + vc.z;
  o.w = (float)a0[3] + (float)a1[3] + (float)a2[3] + (float)a3[3] + vx.w + vb.w + vc.w;
  *(float4*)&out[base] = o;
}

// ---------------- Causal flash attention (v6c) ----------------
__global__ __launch_bounds__(512, 4) void attn_kernel(
    const bf16* __restrict__ Q, const bf16* __restrict__ Kg,
    const bf16* __restrict__ VTg, bf16* __restrict__ O, int ldO)
{
  __shared__ __align__(16) bf16 Ks[4][64][64];
  __shared__ __align__(16) bf16 Vs[4][64][64];
  __shared__ __align__(16) bf16 Ps[8][16][64];

  const int tid = threadIdx.x;
  const int lane = tid & 63, wave = tid >> 6;
  const int g = lane >> 4, c = lane & 15;
  const int L = blockIdx.x;
  const int heavy = (L < 256);
  const int r = heavy ? L : (L - 256);
  const int bh = r >> 3;
  const int qtile = heavy ? (8 + (r & 7)) : (7 - (r & 7));
  const int qw = qtile * 128 + wave * 16;

  const bf16* Qp = Q + (size_t)bh * 2048 * 64;
  const bf16* Kp = Kg + (size_t)bh * 2048 * 64;
  const bf16* Vp = VTg + (size_t)bh * 64 * 2048;

  const int srow = lane >> 3;
  const int schunk = (lane & 7) ^ srow;
  const int svr = wave * 8 + srow;

  bf16x8 qreg[2];
  qreg[0] = *(const bf16x8*)&Qp[(size_t)(qw + c) * 64 + g * 8];
  qreg[1] = *(const bf16x8*)&Qp[(size_t)(qw + c) * 64 + 32 + g * 8];
  bf16x8 ones;
  #pragma unroll
  for (int j = 0; j < 8; ++j) ones[j] = (bf16)1.0f;

  const int cq = c & 7;
  int fo[4][2];
  #pragma unroll
  for (int i = 0; i < 4; ++i)
    #pragma unroll
    for (int kk = 0; kk < 2; ++kk)
      fo[i][kk] = (i * 16 + c) * 64 + (((kk * 4 + g) ^ cq) << 3);
  bf16* pw[4];
  #pragma unroll
  for (int kf = 0; kf < 4; ++kf)
    pw[kf] = &Ps[wave][c][((((kf * 2 + (g >> 1)) ^ cq) << 3)) + ((g & 1) << 2)];
  const bf16* pr[2];
  #pragma unroll
  for (int kk = 0; kk < 2; ++kk)
    pr[kk] = &Ps[wave][c][((kk * 4 + g) ^ cq) << 3];

  bf16* const kdst[4] = {&Ks[0][0][0] + wave * 512, &Ks[1][0][0] + wave * 512,
                         &Ks[2][0][0] + wave * 512, &Ks[3][0][0] + wave * 512};
  bf16* const vdst[4] = {&Vs[0][0][0] + wave * 512, &Vs[1][0][0] + wave * 512,
                         &Vs[2][0][0] + wave * 512, &Vs[3][0][0] + wave * 512};

  f32x4 oacc[4] = {};
  f32x4 lacc = {};
  float m_ = -1e30f;

  const int nkb = 2 * qtile + 2;  // even, >= 2
#define STAGE(j_, B4_) do {                                                         \
    gload_lds16(&Kp[(size_t)((j_) * 64 + svr) * 64 + schunk * 8], kdst[B4_]);       \
    gload_lds16(&Vp[(size_t)svr * 2048 + (j_) * 64 + schunk * 8], vdst[B4_]);       \
  } while (0)

  auto qkt = [&](f32x4* st, const bf16* kt) {
    __builtin_amdgcn_s_setprio(1);
    #pragma unroll
    for (int kf = 0; kf < 4; ++kf) {
      f32x4 z = {};
      z = mfma16(*(const bf16x8*)(kt + fo[kf][0]), qreg[0], z);
      st[kf] = mfma16(*(const bf16x8*)(kt + fo[kf][1]), qreg[1], z);
    }
    __builtin_amdgcn_s_setprio(0);
  };

  auto smpv = [&](const f32x4* st, int j_, const bf16* vt) {
    const int kbase = j_ * 64;
    float v[16];
    if (kbase + 63 > qw) {
      const int qrel = qw + c - kbase;
      #pragma unroll
      for (int kf = 0; kf < 4; ++kf)
        #pragma unroll
        for (int rr = 0; rr < 4; ++rr)
          v[kf * 4 + rr] = (kf * 16 + 4 * g + rr <= qrel) ? st[kf][rr] : -1e30f;
    } else {
      #pragma unroll
      for (int kf = 0; kf < 4; ++kf)
        #pragma unroll
        for (int rr = 0; rr < 4; ++rr)
          v[kf * 4 + rr] = st[kf][rr];
    }
    float u0 = fmaxf(fmaxf(v[0], v[1]), v[2]);
    float u1 = fmaxf(fmaxf(v[3], v[4]), v[5]);
    float u2 = fmaxf(fmaxf(v[6], v[7]), v[8]);
    float u3 = fmaxf(fmaxf(v[9], v[10]), v[11]);
    float u4 = fmaxf(fmaxf(v[12], v[13]), v[14]);
    float tm = fmaxf(fmaxf(fmaxf(u0, u1), u2), fmaxf(fmaxf(u3, u4), v[15]));
    if (__any(tm > m_ + 8.0f)) {
      float tr = fmaxf(tm, __shfl_xor(tm, 16));
      tr = fmaxf(tr, __shfl_xor(tr, 32));
      const float mn = fmaxf(m_, tr);
      const float alpha = __builtin_amdgcn_exp2f(m_ - mn);
      m_ = mn;
      lacc[0] *= alpha; lacc[1] *= alpha; lacc[2] *= alpha; lacc[3] *= alpha;
      #pragma unroll
      for (int df = 0; df < 4; ++df) {
        oacc[df][0] *= alpha; oacc[df][1] *= alpha;
        oacc[df][2] *= alpha; oacc[df][3] *= alpha;
      }
    }
    bf16 pq[16];
    #pragma unroll
    for (int i = 0; i < 16; ++i)
      pq[i] = (bf16)__builtin_amdgcn_exp2f(v[i] - m_);
    #pragma unroll
    for (int kf = 0; kf < 4; ++kf) {
      bf16x4 pk = {pq[kf * 4], pq[kf * 4 + 1], pq[kf * 4 + 2], pq[kf * 4 + 3]};
      *(bf16x4*)pw[kf] = pk;
    }
    bf16x8 pfrag0 = *(const bf16x8*)pr[0];
    bf16x8 pfrag1 = *(const bf16x8*)pr[1];
    __builtin_amdgcn_s_setprio(1);
    #pragma unroll
    for (int df = 0; df < 4; ++df) {
      oacc[df] = mfma16(*(const bf16x8*)(vt + fo[df][0]), pfrag0, oacc[df]);
      oacc[df] = mfma16(*(const bf16x8*)(vt + fo[df][1]), pfrag1, oacc[df]);
    }
    lacc = mfma16(ones, pfrag0, lacc);
    lacc = mfma16(ones, pfrag1, lacc);
    __builtin_amdgcn_s_setprio(0);
  };

#define ABODY(j_, BUF, stC, stN) do {                                          \
    const bool stg_ = ((j_) + 3 < nkb);                                        \
    if (stg_) STAGE((j_) + 3, (((BUF) + 3) & 3));                              \
    if (((j_) + 1) < nkb && ((j_) + 1) * 64 <= qw + 15)                        \
      qkt(stN, &Ks[((BUF) + 1) & 3][0][0]);                                    \
    if ((j_) * 64 <= qw + 15) smpv(stC, (j_), &Vs[(BUF)][0][0]);               \
    if (stg_) { VM("2"); } else { VM("0"); }                                   \
    PH_BAR;                                                                    \
  } while (0)

  f32x4 stA[4], stB[4];
  STAGE(0, 0); STAGE(1, 1); STAGE(2, 2);
  VM("2");   // S0,S1 drained; S2 in flight
  PH_BAR;
  qkt(stA, &Ks[0][0][0]);

  const int nq = nkb >> 2;
  for (int qd = 0; qd < nq; ++qd) {
    const int j0 = 4 * qd;
    ABODY(j0 + 0, 0, stA, stB);
    ABODY(j0 + 1, 1, stB, stA);
    ABODY(j0 + 2, 2, stA, stB);
    ABODY(j0 + 3, 3, stB, stA);
  }
  if (nkb & 2) {
    ABODY(nkb - 2, 0, stA, stB);
    ABODY(nkb - 1, 1, stB, stA);
  }
#undef ABODY
#undef STAGE

  const int b = bh >> 4, h = bh & 15;
  const float inv = 1.0f / lacc[0];
  const int s = qw + c;
  #pragma unroll
  for (int df = 0; df < 4; ++df) {
    bf16x4 o;
    #pragma unroll
    for (int rr = 0; rr < 4; ++rr) o[rr] = (bf16)(oacc[df][rr] * inv);
    *(bf16x4*)&O[(size_t)(b * 2048 + s) * ldO + h * 64 + df * 16 + 4 * g] = o;
  }
}

// ---------------- host orchestration ----------------
extern "C" void kernel_launch(void* const* d_in, const int* in_sizes, int n_in,
                              void* d_out, int out_size, void* d_ws, size_t ws_size,
                              hipStream_t stream) {
  const float* x     = (const float*)d_in[0];
  const float* W_qkv = (const float*)d_in[2];
  const float* b_qkv = (const float*)d_in[3];
  const float* W_o   = (const float*)d_in[4];
  const float* b_o   = (const float*)d_in[5];
  const float* ln1w  = (const float*)d_in[6];
  const float* ln1b  = (const float*)d_in[7];
  const float* ln2w  = (const float*)d_in[8];
  const float* ln2b  = (const float*)d_in[9];
  const float* W1    = (const float*)d_in[10];
  const float* b1    = (const float*)d_in[11];
  const float* W2    = (const float*)d_in[12];
  const float* b2    = (const float*)d_in[13];
  const float* freqs = (const float*)d_in[14];
  float* out = (float*)d_out;

  char* ws = (char*)d_ws;
  const size_t MB = (size_t)1 << 20;
  bf16* h1   = (bf16*)(ws + 0 * MB);
  bf16* h2   = (bf16*)(ws + 8 * MB);
  bf16* wQKV = (bf16*)(ws + 16 * MB);
  bf16* wCat = (bf16*)(ws + 22 * MB);
  bf16* w1   = (bf16*)(ws + 32 * MB);
  bf16* Qb   = (bf16*)(ws + 64 * MB);
  bf16* Kb   = (bf16*)(ws + 72 * MB);
  bf16* VTb  = (bf16*)(ws + 80 * MB);
  bf16* A2   = (bf16*)(ws + 88 * MB);
  bf16* q0   = (bf16*)(ws + 0 * MB);
  bf16* q1   = (bf16*)(ws + 8 * MB);
  bf16* q2   = (bf16*)(ws + 40 * MB);
  bf16* q3   = (bf16*)(ws + 48 * MB);

  ln_cast_all<<<13312, 256, 0, stream>>>(x, ln1w, ln1b, ln2w, ln2b, h1, h2,
                                         W_qkv, W1, W_o, W2, wQKV, w1, wCat);
  gemm256<3><<<192, 512, 0, stream>>>(h1, wQKV, b_qkv, Qb,
                                      Kb, VTb, nullptr, freqs,
                                      1024, 3072, 192, 12, 16);
  attn_kernel<<<512, 512, 0, stream>>>(Qb, Kb, VTb, A2, 5120);
  gemm256<1><<<256, 512, 0, stream>>>(h2, w1, b1, A2 + 1024,
                                      nullptr, nullptr, nullptr, nullptr,
                                      1024, 5120, 256, 16, 16);
  gemm256<2><<<256, 512, 0, stream>>>(A2, wCat, nullptr, q0,
                                      q1, q2, q3, nullptr,
                                      5120, 1024, 64, 4, 20);
  combine_out<<<4096, 256, 0, stream>>>(q0, q1, q2, q3, x, b_o, b2, out);
}